// Round 16
// baseline (279.249 us; speedup 1.0000x reference)
//
#include <hip/hip_runtime.h>

#define BB 2
#define NN 2048
#define DD 256
#define HH 8
#define HD 32
#define EPS 1e-5f
#define L2E 1.4426950408889634f

typedef __attribute__((ext_vector_type(8))) short bf16x8;
typedef __attribute__((ext_vector_type(4))) float f32x4;
typedef __attribute__((ext_vector_type(2))) float f32x2;
typedef __attribute__((ext_vector_type(8))) unsigned short u16x8;

__device__ __forceinline__ float lky(float z){ return fmaxf(z, 0.2f*z); }

__device__ __forceinline__ ushort f2bf(float f){
    union{ float f; unsigned u; } c; c.f = f;
    unsigned r = c.u + 0x7fffu + ((c.u >> 16) & 1u);
    return (ushort)(r >> 16);
}
__device__ __forceinline__ float bf2f(ushort u){
    union{ unsigned u; float f; } c; c.u = ((unsigned)u) << 16; return c.f;
}
__device__ __forceinline__ unsigned cvtpk(float lo, float hi){
    unsigned r;
    asm("v_cvt_pk_bf16_f32 %0, %1, %2" : "=v"(r) : "v"(lo), "v"(hi));
    return r;
}

// K0: blocks 0-7: uqkb[h][d] bf16 (h<8: uq, h>=8: uk), cq/ck f32 — log2(e)-scaled.
//     blocks 8-71: WoT[n][k] = bf16(Wo[k][n])
__global__ void k_prep(const float* __restrict__ Wq, const float* __restrict__ bq,
                       const float* __restrict__ Wk, const float* __restrict__ bk,
                       const float* __restrict__ aa, const float* __restrict__ Wo,
                       ushort* __restrict__ uqkb, float* __restrict__ cq,
                       float* __restrict__ ck, ushort* __restrict__ WoT){
    int t = threadIdx.x;
    if(blockIdx.x < 8){
        int h = blockIdx.x;
        int d = t;
        float accq = 0.f, acck = 0.f;
        #pragma unroll
        for(int k=0; k<HD; k++){
            accq += Wq[(size_t)d*DD + h*HD + k] * aa[h*2*HD + k];
            acck += Wk[(size_t)d*DD + h*HD + k] * aa[h*2*HD + HD + k];
        }
        uqkb[h*DD + d]     = f2bf(accq * L2E);
        uqkb[(8+h)*DD + d] = f2bf(acck * L2E);
        __shared__ float red[64];
        if(d < HD){
            red[d]      = bq[h*HD+d]*aa[h*2*HD+d];
            red[32+d]   = bk[h*HD+d]*aa[h*2*HD+HD+d];
        }
        __syncthreads();
        if(d==0){ float s=0.f; for(int k=0;k<32;k++) s+=red[k];    cq[h]=s*L2E; }
        if(d==1){ float s=0.f; for(int k=0;k<32;k++) s+=red[32+k]; ck[h]=s*L2E; }
    } else {
        int blk = blockIdx.x - 8;     // 0..63
        int wv = t>>6, l = t&63;
        int tile = blk*4 + wv;        // 0..255
        int tr = (tile>>4)*16, tc = (tile&15)*16;
        #pragma unroll
        for(int e=0;e<4;e++){
            int idx = l*4+e;
            int kk = tr + (idx>>4);
            int nn = tc + (idx&15);
            WoT[(size_t)nn*DD + kk] = f2bf(Wo[(size_t)kk*DD + nn]);
        }
    }
}

// K1 fused: 8 rows/block: v^T bf16 projection (f32 math) + MFMA-based sq/skT scores.
__global__ __launch_bounds__(256, 2)
void k_sqskv(const float* __restrict__ x, const float* __restrict__ Wv,
             const float* __restrict__ bv, const ushort* __restrict__ uqkb,
             const float* __restrict__ cq, const float* __restrict__ ck,
             ushort* __restrict__ vT, float* __restrict__ sq,
             float* __restrict__ skT){
    __shared__ float  xL[8][260];    // f32 rows for vproj
    __shared__ ushort xb[16][264];   // bf16 rows for score MFMA (rows 8-15 clamped)
    int t = threadIdx.x;
    int r0 = blockIdx.x * 8;
    int b  = r0 >> 11;
    int j0 = r0 & (NN-1);
    #pragma unroll
    for(int i=0;i<8;i++){
        float v = x[((size_t)r0+i)*DD + t];
        xL[i][t] = v;
        xb[i][t] = f2bf(v);
    }
    #pragma unroll
    for(int i=8;i<16;i++){
        int rr = r0+i; if(rr > BB*NN-1) rr = BB*NN-1;
        xb[i][t] = f2bf(x[(size_t)rr*DD + t]);
    }
    __syncthreads();

    int wv = t>>6, l = t&63;
    // wave 0: scores via MFMA 16x16x32: C[i][n] = sum_k xb[i][k]*uqkb[n][k]
    if(wv == 0){
        int lr = l&15, kg = l>>4;
        f32x4 acc = (f32x4){0.f,0.f,0.f,0.f};
        #pragma unroll
        for(int ks=0; ks<8; ks++){
            bf16x8 a = *reinterpret_cast<const bf16x8*>(&xb[lr][ks*32 + kg*8]);
            bf16x8 bb = *reinterpret_cast<const bf16x8*>(uqkb + (size_t)lr*DD + ks*32 + kg*8);
            acc = __builtin_amdgcn_mfma_f32_16x16x32_bf16(a, bb, acc, 0,0,0);
        }
        #pragma unroll
        for(int rg=0; rg<4; rg++){
            int i = kg*4 + rg;
            if(i < 8){
                int R = r0 + i;
                float vsc = acc[rg];
                if(lr < 8) sq[(size_t)R*HH + lr] = vsc + cq[lr];
                else       skT[((size_t)b*HH + (lr-8))*NN + (R & (NN-1))] = vsc + ck[lr-8];
            }
        }
    }

    // vproj: all threads, thread = col t, 8 rows (f32)
    float acc[8];
    #pragma unroll
    for(int r=0;r<8;r++) acc[r]=0.f;
    for(int k=0;k<DD;k+=4){
        float w0 = Wv[(size_t)k*DD + t];
        float w1 = Wv[(size_t)(k+1)*DD + t];
        float w2 = Wv[(size_t)(k+2)*DD + t];
        float w3 = Wv[(size_t)(k+3)*DD + t];
        #pragma unroll
        for(int r=0;r<8;r++){
            float4 xv = *reinterpret_cast<const float4*>(&xL[r][k]);
            acc[r] += xv.x*w0 + xv.y*w1 + xv.z*w2 + xv.w*w3;
        }
    }
    {
        float bb = bv[t];
        u16x8 pack;
        #pragma unroll
        for(int r=0;r<8;r++) pack[r] = f2bf(acc[r] + bb);
        *reinterpret_cast<u16x8*>(&vT[((size_t)b*DD + t)*NN + j0]) = pack;
    }
}

// K1b: Mk[bh] = max_j skT[bh][j]   (bh = b*8+h, contiguous rows)
__global__ void k_maxsk(const float* __restrict__ skT, float* __restrict__ Mk){
    int bh = blockIdx.x;
    int t = threadIdx.x;
    float m = -1e30f;
    for(int j=t; j<NN; j+=256) m = fmaxf(m, skT[(size_t)bh*NN + j]);
    #pragma unroll
    for(int off=32; off>=1; off>>=1) m = fmaxf(m, __shfl_xor(m, off));
    __shared__ float red[4];
    if((t&63)==0) red[t>>6] = m;
    __syncthreads();
    if(t==0) Mk[bh] = fmaxf(fmaxf(red[0],red[1]), fmaxf(red[2],red[3]));
}

// K2: 2 rows/block, raw adj in, Madj + adj-bitmask out (pack free — adj already read here)
__global__ void k_denom(const int* __restrict__ adj, const float* __restrict__ sq,
                        const float* __restrict__ skT, const float* __restrict__ Mk,
                        float* __restrict__ Madj, unsigned* __restrict__ adjm){
    int r0 = blockIdx.x*2;          // rows r0, r0+1 (same b)
    int b = r0 >> 11;
    int t = threadIdx.x;
    int w = t>>6, l = t&63;
    float sq1[HH], sq2[HH], M1[HH], M2[HH], s1[HH], s2[HH];
    {
        float4 a0 = *reinterpret_cast<const float4*>(&sq[(size_t)r0*HH]);
        float4 a1 = *reinterpret_cast<const float4*>(&sq[(size_t)r0*HH+4]);
        float4 b0 = *reinterpret_cast<const float4*>(&sq[(size_t)(r0+1)*HH]);
        float4 b1 = *reinterpret_cast<const float4*>(&sq[(size_t)(r0+1)*HH+4]);
        float4 m0 = *reinterpret_cast<const float4*>(&Mk[b*HH]);
        float4 m1 = *reinterpret_cast<const float4*>(&Mk[b*HH+4]);
        sq1[0]=a0.x; sq1[1]=a0.y; sq1[2]=a0.z; sq1[3]=a0.w;
        sq1[4]=a1.x; sq1[5]=a1.y; sq1[6]=a1.z; sq1[7]=a1.w;
        sq2[0]=b0.x; sq2[1]=b0.y; sq2[2]=b0.z; sq2[3]=b0.w;
        sq2[4]=b1.x; sq2[5]=b1.y; sq2[6]=b1.z; sq2[7]=b1.w;
        float mk[8] = {m0.x,m0.y,m0.z,m0.w,m1.x,m1.y,m1.z,m1.w};
        #pragma unroll
        for(int h=0;h<HH;h++){
            M1[h] = lky(sq1[h]+mk[h]); M2[h] = lky(sq2[h]+mk[h]);
            s1[h]=0.f; s2[h]=0.f;
        }
    }
    const int* arow1 = adj + (size_t)r0*NN;
    const int* arow2 = adj + ((size_t)r0+1)*NN;
    for(int j0=0; j0<NN; j0+=256){
        int j = j0 + t;
        int a1 = arow1[j];
        int a2 = arow2[j];
        {
            unsigned long long m1b = __ballot(a1 != 0);
            unsigned long long m2b = __ballot(a2 != 0);
            int cw = (j0 >> 5) + w*2;
            if(l == 0){
                adjm[(size_t)r0*64 + cw]       = (unsigned)m1b;
                adjm[((size_t)r0+1)*64 + cw]   = (unsigned)m2b;
            }
            if(l == 32){
                adjm[(size_t)r0*64 + cw + 1]     = (unsigned)(m1b >> 32);
                adjm[((size_t)r0+1)*64 + cw + 1] = (unsigned)(m2b >> 32);
            }
        }
        #pragma unroll
        for(int h=0; h<HH; h++){
            float skv = skT[((size_t)b*HH + h)*NN + j];
            float e1 = exp2f(lky(sq1[h]+skv) - M1[h]);
            float e2 = exp2f(lky(sq2[h]+skv) - M2[h]);
            s1[h] += a1 ? e1 : 0.f;
            s2[h] += a2 ? e2 : 0.f;
        }
    }
    #pragma unroll
    for(int h=0;h<HH;h++){
        #pragma unroll
        for(int off=32; off>=1; off>>=1){
            s1[h] += __shfl_xor(s1[h], off);
            s2[h] += __shfl_xor(s2[h], off);
        }
    }
    __shared__ float red[4][16];
    if(l==0){
        #pragma unroll
        for(int h=0;h<HH;h++){ red[w][h]=s1[h]; red[w][8+h]=s2[h]; }
    }
    __syncthreads();
    if(t < 16){
        float s = red[0][t]+red[1][t]+red[2][t]+red[3][t];
        int h = t & 7;
        if(t < 8) Madj[(size_t)r0*HH + h]     = M1[h] + log2f(s);
        else      Madj[((size_t)r0+1)*HH + h] = M2[h] + log2f(s);
    }
}

// K3: register-fragment k_attn. Each lane computes its OWN MFMA A-fragment's w
// values in registers (no wLDS roundtrip). meanw via padded-LDS f32 atomics,
// readout pipelined into next tile's stage phase. 24.7KB LDS -> 5 blocks/CU.
#define TI 32
#define JT 32
#define JC 8
#define JPC (NN/JC)   // 256
#define SUMS 33        // sumbuf row stride (pad)

__global__ __launch_bounds__(256, 5)
void k_attn(const unsigned* __restrict__ adjm, const float* __restrict__ sq,
            const float* __restrict__ skT, const float* __restrict__ Madj,
            const ushort* __restrict__ vT, float* __restrict__ meanw,
            ushort* __restrict__ attp){
    __shared__ __align__(16) char smem[24704];
    ushort (*vLDS)[40] = (ushort (*)[40])smem;            // [256][40] = 20480B
    float* sumb = (float*)(smem + 20480);                  // [32][33]  = 4224B
    float* fbH  = (float*)smem;                            // epilogue alias [16][260]

    int t  = threadIdx.x;
    int it = blockIdx.x;
    int b  = blockIdx.y;
    int jc = blockIdx.z;
    int i0 = it*TI;
    int R0 = b*NN + i0;

    int wid = t >> 6;          // wave -> heads 2wid, 2wid+1
    int l   = t & 63;
    int lr  = l & 15;
    int kg  = l >> 4;
    int h0  = wid*2;

    // per-lane row params: rows lr (A) and 16+lr (B), heads h0,h0+1
    float2 sqA = *reinterpret_cast<const float2*>(&sq[(size_t)(R0+lr)*HH + h0]);
    float2 sqB = *reinterpret_cast<const float2*>(&sq[(size_t)(R0+16+lr)*HH + h0]);
    float2 MA  = *reinterpret_cast<const float2*>(&Madj[(size_t)(R0+lr)*HH + h0]);
    float2 MB  = *reinterpret_cast<const float2*>(&Madj[(size_t)(R0+16+lr)*HH + h0]);

    f32x4 acc[2][2][2];        // [head-in-wave][mi][ni]
    #pragma unroll
    for(int hh=0;hh<2;hh++)
        #pragma unroll
        for(int mi=0;mi<2;mi++)
            #pragma unroll
            for(int ni=0;ni<2;ni++) acc[hh][mi][ni] = (f32x4){0.f,0.f,0.f,0.f};

    const ushort* vsrc = vT + ((size_t)b*DD + t)*NN;
    const float* sk0base = skT + ((size_t)b*HH + h0)*NN;
    const float* sk1base = skT + ((size_t)b*HH + h0 + 1)*NN;
    const unsigned* mAp = adjm + (size_t)(R0+lr)*64 + jc*8;
    const unsigned* mBp = adjm + (size_t)(R0+16+lr)*64 + jc*8;

    // initial zero of sumb (incl. padding)
    for(int p=t; p<32*SUMS; p+=256) sumb[p] = 0.f;

    float pmA[8], pmB[8];
    union { bf16x8 v; unsigned u[4]; } pa0, pa1, pb0, pb1;

    int ri = t >> 3;              // meanw readout row
    int rq = (t & 7) * 4;         // meanw readout col base

    for(int jt=0; jt<JPC/JT; jt++){
        int jb = jc*JPC + jt*JT;

        __syncthreads();   // A: prev atomics+MFMA done; vLDS free; sumb(jt-1) final

        // B1: stage vLDS
        {
            const ushort* src = vsrc + jb;
            u16x8 v0 = *reinterpret_cast<const u16x8*>(src);
            u16x8 v1 = *reinterpret_cast<const u16x8*>(src+8);
            u16x8 v2 = *reinterpret_cast<const u16x8*>(src+16);
            u16x8 v3 = *reinterpret_cast<const u16x8*>(src+24);
            *reinterpret_cast<u16x8*>(&vLDS[t][0])  = v0;
            *reinterpret_cast<u16x8*>(&vLDS[t][8])  = v1;
            *reinterpret_cast<u16x8*>(&vLDS[t][16]) = v2;
            *reinterpret_cast<u16x8*>(&vLDS[t][24]) = v3;
        }
        // B2: pipelined meanw readout for jt-1 (+rezero own slots)
        if(jt > 0){
            int base = ri*SUMS + rq;
            float4 mw;
            mw.x = sumb[base+0]; mw.y = sumb[base+1];
            mw.z = sumb[base+2]; mw.w = sumb[base+3];
            sumb[base+0]=0.f; sumb[base+1]=0.f; sumb[base+2]=0.f; sumb[base+3]=0.f;
            mw.x*=0.125f; mw.y*=0.125f; mw.z*=0.125f; mw.w*=0.125f;
            *reinterpret_cast<float4*>(&meanw[((size_t)(R0+ri))*NN + jb - JT + rq]) = mw;
        }

        // C: compute w fragment in registers
        {
            float4 s0a = *reinterpret_cast<const float4*>(&sk0base[jb + kg*8]);
            float4 s0b = *reinterpret_cast<const float4*>(&sk0base[jb + kg*8 + 4]);
            float4 s1a = *reinterpret_cast<const float4*>(&sk1base[jb + kg*8]);
            float4 s1b = *reinterpret_cast<const float4*>(&sk1base[jb + kg*8 + 4]);
            unsigned byA = (mAp[jt] >> (kg*8)) & 0xffu;
            unsigned byB = (mBp[jt] >> (kg*8)) & 0xffu;
            float sk0[8] = {s0a.x,s0a.y,s0a.z,s0a.w,s0b.x,s0b.y,s0b.z,s0b.w};
            float sk1[8] = {s1a.x,s1a.y,s1a.z,s1a.w,s1b.x,s1b.y,s1b.z,s1b.w};
            float wA0[8], wA1[8], wB0[8], wB1[8];
            #pragma unroll
            for(int e=0;e<8;e++){
                bool bA = (byA>>e)&1u, bB = (byB>>e)&1u;
                float eA0 = exp2f(lky(sqA.x+sk0[e]) - MA.x);
                float eA1 = exp2f(lky(sqA.y+sk1[e]) - MA.y);
                float eB0 = exp2f(lky(sqB.x+sk0[e]) - MB.x);
                float eB1 = exp2f(lky(sqB.y+sk1[e]) - MB.y);
                wA0[e] = bA ? eA0 : 0.f;
                wA1[e] = bA ? eA1 : 0.f;
                wB0[e] = bB ? eB0 : 0.f;
                wB1[e] = bB ? eB1 : 0.f;
                pmA[e] = wA0[e] + wA1[e];
                pmB[e] = wB0[e] + wB1[e];
            }
            #pragma unroll
            for(int p=0;p<4;p++){
                pa0.u[p] = cvtpk(wA0[2*p], wA0[2*p+1]);
                pa1.u[p] = cvtpk(wA1[2*p], wA1[2*p+1]);
                pb0.u[p] = cvtpk(wB0[2*p], wB0[2*p+1]);
                pb1.u[p] = cvtpk(wB1[2*p], wB1[2*p+1]);
            }
        }

        __syncthreads();   // D: vLDS staged; sumb rezeroed

        // E: meanw atomics + MFMA
        #pragma unroll
        for(int e=0;e<8;e++)
            atomicAdd(&sumb[lr*SUMS + kg*8 + e], pmA[e]);
        #pragma unroll
        for(int e=0;e<8;e++)
            atomicAdd(&sumb[(16+lr)*SUMS + kg*8 + e], pmB[e]);

        {
            bf16x8 b00 = *reinterpret_cast<const bf16x8*>(&vLDS[h0*HD + lr][kg*8]);
            bf16x8 b01 = *reinterpret_cast<const bf16x8*>(&vLDS[h0*HD + 16 + lr][kg*8]);
            bf16x8 b10 = *reinterpret_cast<const bf16x8*>(&vLDS[(h0+1)*HD + lr][kg*8]);
            bf16x8 b11 = *reinterpret_cast<const bf16x8*>(&vLDS[(h0+1)*HD + 16 + lr][kg*8]);
            acc[0][0][0] = __builtin_amdgcn_mfma_f32_16x16x32_bf16(pa0.v, b00, acc[0][0][0], 0,0,0);
            acc[0][0][1] = __builtin_amdgcn_mfma_f32_16x16x32_bf16(pa0.v, b01, acc[0][0][1], 0,0,0);
            acc[0][1][0] = __builtin_amdgcn_mfma_f32_16x16x32_bf16(pb0.v, b00, acc[0][1][0], 0,0,0);
            acc[0][1][1] = __builtin_amdgcn_mfma_f32_16x16x32_bf16(pb0.v, b01, acc[0][1][1], 0,0,0);
            acc[1][0][0] = __builtin_amdgcn_mfma_f32_16x16x32_bf16(pa1.v, b10, acc[1][0][0], 0,0,0);
            acc[1][0][1] = __builtin_amdgcn_mfma_f32_16x16x32_bf16(pa1.v, b11, acc[1][0][1], 0,0,0);
            acc[1][1][0] = __builtin_amdgcn_mfma_f32_16x16x32_bf16(pb1.v, b10, acc[1][1][0], 0,0,0);
            acc[1][1][1] = __builtin_amdgcn_mfma_f32_16x16x32_bf16(pb1.v, b11, acc[1][1][1], 0,0,0);
        }
    }

    __syncthreads();   // last tile's atomics+MFMA done
    // final meanw readout (jt = last)
    {
        int base = ri*SUMS + rq;
        float4 mw;
        mw.x = sumb[base+0]*0.125f; mw.y = sumb[base+1]*0.125f;
        mw.z = sumb[base+2]*0.125f; mw.w = sumb[base+3]*0.125f;
        *reinterpret_cast<float4*>(&meanw[((size_t)(R0+ri))*NN + jc*JPC + JPC - JT + rq]) = mw;
    }
    __syncthreads();   // sumb reads done; vLDS reads long done -> fbH alias safe

    // Epilogue: two 16-row halves through fbH (f32 [16][260], 2-way-free writes)
    #pragma unroll
    for(int half=0; half<2; half++){
        #pragma unroll
        for(int hh=0;hh<2;hh++)
            #pragma unroll
            for(int ni=0;ni<2;ni++)
                #pragma unroll
                for(int rg=0; rg<4; rg++){
                    int iL = kg*4 + rg;
                    int d = (wid*2+hh)*HD + ni*16 + lr;
                    fbH[iL*260 + d] = acc[hh][half][ni][rg];
                }
        __syncthreads();
        {
            int iL = t >> 4;             // 0..15
            int d0 = (t & 15) * 16;      // 16 floats per thread
            size_t orow = ((size_t)(jc*BB + b)*NN + i0 + half*16 + iL)*DD + d0;
            float4 f0 = *reinterpret_cast<const float4*>(&fbH[iL*260 + d0]);
            float4 f1 = *reinterpret_cast<const float4*>(&fbH[iL*260 + d0 + 4]);
            float4 f2 = *reinterpret_cast<const float4*>(&fbH[iL*260 + d0 + 8]);
            float4 f3 = *reinterpret_cast<const float4*>(&fbH[iL*260 + d0 + 12]);
            uint4 pk0, pk1;
            pk0.x = cvtpk(f0.x,f0.y); pk0.y = cvtpk(f0.z,f0.w);
            pk0.z = cvtpk(f1.x,f1.y); pk0.w = cvtpk(f1.z,f1.w);
            pk1.x = cvtpk(f2.x,f2.y); pk1.y = cvtpk(f2.z,f2.w);
            pk1.z = cvtpk(f3.x,f3.y); pk1.w = cvtpk(f3.z,f3.w);
            *reinterpret_cast<uint4*>(&attp[orow])     = pk0;
            *reinterpret_cast<uint4*>(&attp[orow + 8]) = pk1;
        }
        __syncthreads();
    }
}

// K4: out = LN( (sum attp) @ Wo + bo + x ) — GEMM via MFMA with bf16 WoT.
__global__ __launch_bounds__(256, 2)
void k_out(const ushort* __restrict__ attp, const float* __restrict__ x,
           const ushort* __restrict__ WoT, const float* __restrict__ bo,
           const float* __restrict__ g, const float* __restrict__ bln,
           float* __restrict__ out){
    __shared__ ushort ab[16][264];   // bf16 attended (rows 8-15 zero)
    __shared__ float fbo[8][260];    // GEMM result / LN scratch
    __shared__ float ps[8][32][2];
    __shared__ float muL[8], rsL[8];
    int t = threadIdx.x;
    int r0 = blockIdx.x*8;
    int b  = r0 >> 11;
    int j0 = r0 & (NN-1);

    {
        int rr = t >> 5;
        int d0 = (t & 31) * 8;
        float s8[8];
        #pragma unroll
        for(int e=0;e<8;e++) s8[e]=0.f;
        #pragma unroll
        for(int jc=0; jc<JC; jc++){
            u16x8 v = *reinterpret_cast<const u16x8*>(&attp[((size_t)(jc*BB + b)*NN + j0 + rr)*DD + d0]);
            #pragma unroll
            for(int e=0;e<8;e++) s8[e] += bf2f(v[e]);
        }
        u16x8 pack;
        #pragma unroll
        for(int e=0;e<8;e++) pack[e] = f2bf(s8[e]);
        *reinterpret_cast<u16x8*>(&ab[rr][d0]) = pack;
        u16x8 z = {0,0,0,0,0,0,0,0};
        *reinterpret_cast<u16x8*>(&ab[8+rr][d0]) = z;
    }
    __syncthreads();

    {
        int wv = t>>6, l = t&63, lr = l&15, kg = l>>4;
        f32x4 acc0 = (f32x4){0.f,0.f,0.f,0.f};
        f32x4 acc1 = (f32x4){0.f,0.f,0.f,0.f};
        f32x4 acc2 = (f32x4){0.f,0.f,0.f,0.f};
        f32x4 acc3 = (f32x4){0.f,0.f,0.f,0.f};
        #pragma unroll
        for(int ks=0; ks<8; ks++){
            bf16x8 a = *reinterpret_cast<const bf16x8*>(&ab[lr][ks*32 + kg*8]);
            bf16x8 b0 = *reinterpret_cast<const bf16x8*>(WoT + (size_t)((wv*4+0)*16 + lr)*DD + ks*32 + kg*8);
            bf16x8 b1 = *reinterpret_cast<const bf16x8*>(WoT + (size_t)((wv*4+1)*16 + lr)*DD + ks*32 + kg*8);
            bf16x8 b2 = *reinterpret_cast<const bf16x8*>(WoT + (size_t)((wv*4+2)*16 + lr)*DD + ks*32 + kg*8);
            bf16x8 b3 = *reinterpret_cast<const bf16x8*>(WoT + (size_t)((wv*4+3)*16 + lr)*DD + ks*32 + kg*8);
            acc0 = __builtin_amdgcn_mfma_f32_16x16x32_bf16(a, b0, acc0, 0,0,0);
            acc1 = __builtin_amdgcn_mfma_f32_16x16x32_bf16(a, b1, acc1, 0,0,0);
            acc2 = __builtin_amdgcn_mfma_f32_16x16x32_bf16(a, b2, acc2, 0,0,0);
            acc3 = __builtin_amdgcn_mfma_f32_16x16x32_bf16(a, b3, acc3, 0,0,0);
        }
        #pragma unroll
        for(int rg=0; rg<4; rg++){
            int i = kg*4 + rg;
            if(i < 8){
                fbo[i][(wv*4+0)*16 + lr] = acc0[rg];
                fbo[i][(wv*4+1)*16 + lr] = acc1[rg];
                fbo[i][(wv*4+2)*16 + lr] = acc2[rg];
                fbo[i][(wv*4+3)*16 + lr] = acc3[rg];
            }
        }
    }
    __syncthreads();

    float accr[8];
    #pragma unroll
    for(int r=0;r<8;r++) accr[r] = fbo[r][t] + bo[t] + x[((size_t)r0+r)*DD + t];
    __syncthreads();
    #pragma unroll
    for(int r=0;r<8;r++) fbo[r][t] = accr[r];
    __syncthreads();
    {
        int rr = t>>5, seg = t&31;
        float s=0.f, sqs=0.f;
        #pragma unroll
        for(int e=0;e<8;e++){
            float y = fbo[rr][seg*8+e];
            s += y; sqs += y*y;
        }
        ps[rr][seg][0]=s; ps[rr][seg][1]=sqs;
    }
    __syncthreads();
    if(t<8){
        float s=0.f, sqs=0.f;
        #pragma unroll
        for(int e=0;e<32;e++){ s+=ps[t][e][0]; sqs+=ps[t][e][1]; }
        float mu = s/256.f;
        float var = sqs/256.f - mu*mu;
        muL[t]=mu; rsL[t]=rsqrtf(var+EPS);
    }
    __syncthreads();
    float gg = g[t], bl = bln[t];
    #pragma unroll
    for(int r=0;r<8;r++){
        out[((size_t)r0+r)*DD + t] = (accr[r]-muL[r])*rsL[r]*gg + bl;
    }
}

extern "C" void kernel_launch(void* const* d_in, const int* in_sizes, int n_in,
                              void* d_out, int out_size, void* d_ws, size_t ws_size,
                              hipStream_t stream) {
    const float* x    = (const float*)d_in[0];
    const int*   adj  = (const int*)d_in[1];
    const float* Wq   = (const float*)d_in[2];
    const float* bq   = (const float*)d_in[3];
    const float* Wk   = (const float*)d_in[4];
    const float* bk   = (const float*)d_in[5];
    const float* Wv   = (const float*)d_in[6];
    const float* bv   = (const float*)d_in[7];
    const float* aa   = (const float*)d_in[8];
    const float* Wo   = (const float*)d_in[9];
    const float* bo   = (const float*)d_in[10];
    const float* lng  = (const float*)d_in[11];
    const float* lnb  = (const float*)d_in[12];

    float* out0  = (float*)d_out;                  // (B,N,D)
    float* meanw = out0 + (size_t)BB*NN*DD;        // (B,N,N)

    char* wsb = (char*)d_ws;
    float* cq   = (float*)wsb;                                    // 16
    float* ck   = cq + 16;                                        // 16
    float* Mk   = ck + 16;                                        // 16 (+pad)
    float* sqv  = Mk + 80;                                        // 32768
    float* skT  = sqv + 32768;                                    // 32768
    float* Madj = skT + 32768;                                    // 32768
    unsigned* adjm = (unsigned*)(Madj + 32768);                   // BB*NN*64 u32 = 1MB
    ushort* uqkb= (ushort*)(adjm + (size_t)BB*NN*64);             // 16*256 u16
    ushort* WoT = uqkb + 16*DD;                                   // 256*256 u16
    ushort* vT  = WoT + (size_t)DD*DD;                            // BB*DD*NN u16
    ushort* attp= vT + (size_t)BB*DD*NN;                          // JC*BB*NN*DD u16

    k_prep<<<72, 256, 0, stream>>>(Wq, bq, Wk, bk, aa, Wo, uqkb, cq, ck, WoT);
    k_sqskv<<<(BB*NN)/8, 256, 0, stream>>>(x, Wv, bv, uqkb, cq, ck, vT, sqv, skT);
    k_maxsk<<<BB*HH, 256, 0, stream>>>(skT, Mk);
    k_denom<<<(BB*NN)/2, 256, 0, stream>>>(adj, sqv, skT, Mk, Madj, adjm);
    k_attn<<<dim3(NN/TI, BB, JC), 256, 0, stream>>>(adjm, sqv, skT, Madj, vT, meanw, attp);
    k_out<<<(BB*NN)/8, 256, 0, stream>>>(attp, x, WoT, bo, lng, lnb, out0);
}

// Round 17
// 117.968 us; speedup vs baseline: 2.3672x; 2.3672x over previous
//
#include <hip/hip_runtime.h>

#define BB 2
#define NN 2048
#define DD 256
#define HH 8
#define HD 32
#define EPS 1e-5f
#define L2E 1.4426950408889634f

typedef __attribute__((ext_vector_type(8))) short bf16x8;
typedef __attribute__((ext_vector_type(4))) float f32x4;
typedef __attribute__((ext_vector_type(2))) float f32x2;
typedef __attribute__((ext_vector_type(8))) unsigned short u16x8;

__device__ __forceinline__ float lky(float z){ return fmaxf(z, 0.2f*z); }

__device__ __forceinline__ ushort f2bf(float f){
    union{ float f; unsigned u; } c; c.f = f;
    unsigned r = c.u + 0x7fffu + ((c.u >> 16) & 1u);
    return (ushort)(r >> 16);
}
__device__ __forceinline__ float bf2f(ushort u){
    union{ unsigned u; float f; } c; c.u = ((unsigned)u) << 16; return c.f;
}
__device__ __forceinline__ unsigned cvtpk(float lo, float hi){
    unsigned r;
    asm("v_cvt_pk_bf16_f32 %0, %1, %2" : "=v"(r) : "v"(lo), "v"(hi));
    return r;
}

// K0: blocks 0-7: uqkb[h][d] bf16 (h<8: uq, h>=8: uk), cq/ck f32 — log2(e)-scaled.
//     blocks 8-71: WoT[n][k] = bf16(Wo[k][n])
__global__ void k_prep(const float* __restrict__ Wq, const float* __restrict__ bq,
                       const float* __restrict__ Wk, const float* __restrict__ bk,
                       const float* __restrict__ aa, const float* __restrict__ Wo,
                       ushort* __restrict__ uqkb, float* __restrict__ cq,
                       float* __restrict__ ck, ushort* __restrict__ WoT){
    int t = threadIdx.x;
    if(blockIdx.x < 8){
        int h = blockIdx.x;
        int d = t;
        float accq = 0.f, acck = 0.f;
        #pragma unroll
        for(int k=0; k<HD; k++){
            accq += Wq[(size_t)d*DD + h*HD + k] * aa[h*2*HD + k];
            acck += Wk[(size_t)d*DD + h*HD + k] * aa[h*2*HD + HD + k];
        }
        uqkb[h*DD + d]     = f2bf(accq * L2E);
        uqkb[(8+h)*DD + d] = f2bf(acck * L2E);
        __shared__ float red[64];
        if(d < HD){
            red[d]      = bq[h*HD+d]*aa[h*2*HD+d];
            red[32+d]   = bk[h*HD+d]*aa[h*2*HD+HD+d];
        }
        __syncthreads();
        if(d==0){ float s=0.f; for(int k=0;k<32;k++) s+=red[k];    cq[h]=s*L2E; }
        if(d==1){ float s=0.f; for(int k=0;k<32;k++) s+=red[32+k]; ck[h]=s*L2E; }
    } else {
        int blk = blockIdx.x - 8;     // 0..63
        int wv = t>>6, l = t&63;
        int tile = blk*4 + wv;        // 0..255
        int tr = (tile>>4)*16, tc = (tile&15)*16;
        #pragma unroll
        for(int e=0;e<4;e++){
            int idx = l*4+e;
            int kk = tr + (idx>>4);
            int nn = tc + (idx&15);
            WoT[(size_t)nn*DD + kk] = f2bf(Wo[(size_t)kk*DD + nn]);
        }
    }
}

// K1 fused: 8 rows/block: v^T bf16 projection (f32 math) + MFMA-based sq/skH scores.
__global__ __launch_bounds__(256, 2)
void k_sqskv(const float* __restrict__ x, const float* __restrict__ Wv,
             const float* __restrict__ bv, const ushort* __restrict__ uqkb,
             const float* __restrict__ cq, const float* __restrict__ ck,
             ushort* __restrict__ vT, float* __restrict__ sq,
             float* __restrict__ skH){
    __shared__ float  xL[8][260];    // f32 rows for vproj
    __shared__ ushort xb[16][264];   // bf16 rows for score MFMA (rows 8-15 clamped)
    int t = threadIdx.x;
    int r0 = blockIdx.x * 8;
    int b  = r0 >> 11;
    int j0 = r0 & (NN-1);
    #pragma unroll
    for(int i=0;i<8;i++){
        float v = x[((size_t)r0+i)*DD + t];
        xL[i][t] = v;
        xb[i][t] = f2bf(v);
    }
    #pragma unroll
    for(int i=8;i<16;i++){
        int rr = r0+i; if(rr > BB*NN-1) rr = BB*NN-1;
        xb[i][t] = f2bf(x[(size_t)rr*DD + t]);
    }
    __syncthreads();

    int wv = t>>6, l = t&63;
    // wave 0: scores via MFMA 16x16x32: C[i][n] = sum_k xb[i][k]*uqkb[n][k]
    if(wv == 0){
        int lr = l&15, kg = l>>4;
        f32x4 acc = (f32x4){0.f,0.f,0.f,0.f};
        #pragma unroll
        for(int ks=0; ks<8; ks++){
            bf16x8 a = *reinterpret_cast<const bf16x8*>(&xb[lr][ks*32 + kg*8]);
            bf16x8 bb = *reinterpret_cast<const bf16x8*>(uqkb + (size_t)lr*DD + ks*32 + kg*8);
            acc = __builtin_amdgcn_mfma_f32_16x16x32_bf16(a, bb, acc, 0,0,0);
        }
        #pragma unroll
        for(int rg=0; rg<4; rg++){
            int i = kg*4 + rg;
            if(i < 8){
                int R = r0 + i;
                float vsc = acc[rg];
                if(lr < 8) sq[(size_t)R*HH + lr] = vsc + cq[lr];
                else       skH[((size_t)b*NN + (R & (NN-1)))*HH + (lr-8)] = vsc + ck[lr-8];
            }
        }
    }

    // vproj: all threads, thread = col t, 8 rows (f32)
    float acc[8];
    #pragma unroll
    for(int r=0;r<8;r++) acc[r]=0.f;
    for(int k=0;k<DD;k+=4){
        float w0 = Wv[(size_t)k*DD + t];
        float w1 = Wv[(size_t)(k+1)*DD + t];
        float w2 = Wv[(size_t)(k+2)*DD + t];
        float w3 = Wv[(size_t)(k+3)*DD + t];
        #pragma unroll
        for(int r=0;r<8;r++){
            float4 xv = *reinterpret_cast<const float4*>(&xL[r][k]);
            acc[r] += xv.x*w0 + xv.y*w1 + xv.z*w2 + xv.w*w3;
        }
    }
    {
        float bb = bv[t];
        u16x8 pack;
        #pragma unroll
        for(int r=0;r<8;r++) pack[r] = f2bf(acc[r] + bb);
        *reinterpret_cast<u16x8*>(&vT[((size_t)b*DD + t)*NN + j0]) = pack;
    }
}

// K1b: Mk[b][h] = max_j skH[b][j][h]
__global__ void k_maxsk(const float* __restrict__ skH, float* __restrict__ Mk){
    int b = blockIdx.x >> 3, h = blockIdx.x & 7;
    int t = threadIdx.x;
    float m = -1e30f;
    for(int j=t; j<NN; j+=256) m = fmaxf(m, skH[((size_t)b*NN + j)*HH + h]);
    #pragma unroll
    for(int off=32; off>=1; off>>=1) m = fmaxf(m, __shfl_xor(m, off));
    __shared__ float red[4];
    if((t&63)==0) red[t>>6] = m;
    __syncthreads();
    if(t==0) Mk[blockIdx.x] = fmaxf(fmaxf(red[0],red[1]), fmaxf(red[2],red[3]));
}

// K2: 2 rows/block, raw adj in, Madj + adj-bitmask out (pack free — adj already read here)
__global__ void k_denom(const int* __restrict__ adj, const float* __restrict__ sq,
                        const float* __restrict__ skH, const float* __restrict__ Mk,
                        float* __restrict__ Madj, unsigned* __restrict__ adjm){
    int r0 = blockIdx.x*2;          // rows r0, r0+1 (same b)
    int b = r0 >> 11;
    int t = threadIdx.x;
    int w = t>>6, l = t&63;
    float sq1[HH], sq2[HH], M1[HH], M2[HH], s1[HH], s2[HH];
    {
        float4 a0 = *reinterpret_cast<const float4*>(&sq[(size_t)r0*HH]);
        float4 a1 = *reinterpret_cast<const float4*>(&sq[(size_t)r0*HH+4]);
        float4 b0 = *reinterpret_cast<const float4*>(&sq[(size_t)(r0+1)*HH]);
        float4 b1 = *reinterpret_cast<const float4*>(&sq[(size_t)(r0+1)*HH+4]);
        float4 m0 = *reinterpret_cast<const float4*>(&Mk[b*HH]);
        float4 m1 = *reinterpret_cast<const float4*>(&Mk[b*HH+4]);
        sq1[0]=a0.x; sq1[1]=a0.y; sq1[2]=a0.z; sq1[3]=a0.w;
        sq1[4]=a1.x; sq1[5]=a1.y; sq1[6]=a1.z; sq1[7]=a1.w;
        sq2[0]=b0.x; sq2[1]=b0.y; sq2[2]=b0.z; sq2[3]=b0.w;
        sq2[4]=b1.x; sq2[5]=b1.y; sq2[6]=b1.z; sq2[7]=b1.w;
        float mk[8] = {m0.x,m0.y,m0.z,m0.w,m1.x,m1.y,m1.z,m1.w};
        #pragma unroll
        for(int h=0;h<HH;h++){
            M1[h] = lky(sq1[h]+mk[h]); M2[h] = lky(sq2[h]+mk[h]);
            s1[h]=0.f; s2[h]=0.f;
        }
    }
    const int* arow1 = adj + (size_t)r0*NN;
    const int* arow2 = adj + ((size_t)r0+1)*NN;
    for(int j0=0; j0<NN; j0+=256){
        int j = j0 + t;
        int a1 = arow1[j];
        int a2 = arow2[j];
        {
            unsigned long long m1b = __ballot(a1 != 0);
            unsigned long long m2b = __ballot(a2 != 0);
            int cw = (j0 >> 5) + w*2;
            if(l == 0){
                adjm[(size_t)r0*64 + cw]       = (unsigned)m1b;
                adjm[((size_t)r0+1)*64 + cw]   = (unsigned)m2b;
            }
            if(l == 32){
                adjm[(size_t)r0*64 + cw + 1]     = (unsigned)(m1b >> 32);
                adjm[((size_t)r0+1)*64 + cw + 1] = (unsigned)(m2b >> 32);
            }
        }
        float4 v0 = *reinterpret_cast<const float4*>(&skH[((size_t)b*NN + j)*HH]);
        float4 v1 = *reinterpret_cast<const float4*>(&skH[((size_t)b*NN + j)*HH+4]);
        float sk[8] = {v0.x,v0.y,v0.z,v0.w,v1.x,v1.y,v1.z,v1.w};
        #pragma unroll
        for(int h=0; h<HH; h++){
            float e1 = exp2f(lky(sq1[h]+sk[h]) - M1[h]);
            float e2 = exp2f(lky(sq2[h]+sk[h]) - M2[h]);
            s1[h] += a1 ? e1 : 0.f;
            s2[h] += a2 ? e2 : 0.f;
        }
    }
    #pragma unroll
    for(int h=0;h<HH;h++){
        #pragma unroll
        for(int off=32; off>=1; off>>=1){
            s1[h] += __shfl_xor(s1[h], off);
            s2[h] += __shfl_xor(s2[h], off);
        }
    }
    __shared__ float red[4][16];
    if(l==0){
        #pragma unroll
        for(int h=0;h<HH;h++){ red[w][h]=s1[h]; red[w][8+h]=s2[h]; }
    }
    __syncthreads();
    if(t < 16){
        float s = red[0][t]+red[1][t]+red[2][t]+red[3][t];
        int h = t & 7;
        if(t < 8) Madj[(size_t)r0*HH + h]     = M1[h] + log2f(s);
        else      Madj[((size_t)r0+1)*HH + h] = M2[h] + log2f(s);
    }
}

// K3 (R13/R15 verified variant): adjm bitmask, loads after barrier, XOR-swizzled epilogue.
#define TI 32
#define JT 32
#define JC 8
#define JPC (NN/JC)   // 256

__global__ __launch_bounds__(256, 4)
void k_attn(const unsigned* __restrict__ adjm, const float* __restrict__ sq,
            const float* __restrict__ skH, const float* __restrict__ Madj,
            const ushort* __restrict__ vT, float* __restrict__ meanw,
            ushort* __restrict__ attp){
    __shared__ __align__(16) char smem[40960];
    ushort (*wLDS)[TI][40] = (ushort (*)[TI][40])smem;           // [h][i][j] 20480B
    ushort (*vLDS)[40]     = (ushort (*)[40])(smem + 20480);     // [d][j]    20480B
    float* fb = (float*)smem;                                     // epilogue 32KB

    int t  = threadIdx.x;
    int it = blockIdx.x;
    int b  = blockIdx.y;
    int jc = blockIdx.z;
    int i0 = it*TI;
    int R0 = b*NN + i0;

    int ia = t >> 4;
    int jp = t & 15;
    int jj = jp*2;

    float sq1[8], sq2[8], M1[8], M2[8];
    {
        float4 a0 = *reinterpret_cast<const float4*>(&sq[(size_t)(R0+ia)*HH]);
        float4 a1 = *reinterpret_cast<const float4*>(&sq[(size_t)(R0+ia)*HH+4]);
        float4 b0 = *reinterpret_cast<const float4*>(&sq[(size_t)(R0+16+ia)*HH]);
        float4 b1 = *reinterpret_cast<const float4*>(&sq[(size_t)(R0+16+ia)*HH+4]);
        sq1[0]=a0.x; sq1[1]=a0.y; sq1[2]=a0.z; sq1[3]=a0.w;
        sq1[4]=a1.x; sq1[5]=a1.y; sq1[6]=a1.z; sq1[7]=a1.w;
        sq2[0]=b0.x; sq2[1]=b0.y; sq2[2]=b0.z; sq2[3]=b0.w;
        sq2[4]=b1.x; sq2[5]=b1.y; sq2[6]=b1.z; sq2[7]=b1.w;
        float4 c0 = *reinterpret_cast<const float4*>(&Madj[(size_t)(R0+ia)*HH]);
        float4 c1 = *reinterpret_cast<const float4*>(&Madj[(size_t)(R0+ia)*HH+4]);
        float4 d0 = *reinterpret_cast<const float4*>(&Madj[(size_t)(R0+16+ia)*HH]);
        float4 d1 = *reinterpret_cast<const float4*>(&Madj[(size_t)(R0+16+ia)*HH+4]);
        M1[0]=c0.x; M1[1]=c0.y; M1[2]=c0.z; M1[3]=c0.w;
        M1[4]=c1.x; M1[5]=c1.y; M1[6]=c1.z; M1[7]=c1.w;
        M2[0]=d0.x; M2[1]=d0.y; M2[2]=d0.z; M2[3]=d0.w;
        M2[4]=d1.x; M2[5]=d1.y; M2[6]=d1.z; M2[7]=d1.w;
    }

    int wid = t >> 6;
    int l   = t & 63;
    int lr  = l & 15;
    int kg  = l >> 4;

    f32x4 acc[2][2][2];
    #pragma unroll
    for(int hh=0;hh<2;hh++)
        #pragma unroll
        for(int mi=0;mi<2;mi++)
            #pragma unroll
            for(int ni=0;ni<2;ni++) acc[hh][mi][ni] = (f32x4){0.f,0.f,0.f,0.f};

    const ushort* vsrc = vT + ((size_t)b*DD + t)*NN;
    const float* skbase = skH + (size_t)b*NN*HH;
    const unsigned* mArow = adjm + (size_t)(R0+ia)*64 + jc*8;
    const unsigned* mBrow = adjm + (size_t)(R0+16+ia)*64 + jc*8;

    for(int jt=0; jt<JPC/JT; jt++){
        int jb = jc*JPC + jt*JT;

        __syncthreads();   // prev tile MFMA done reading wLDS/vLDS

        // stage v to LDS (loads AFTER barrier — proven placement)
        {
            const ushort* src = vsrc + jb;
            u16x8 v0 = *reinterpret_cast<const u16x8*>(src);
            u16x8 v1 = *reinterpret_cast<const u16x8*>(src+8);
            u16x8 v2 = *reinterpret_cast<const u16x8*>(src+16);
            u16x8 v3 = *reinterpret_cast<const u16x8*>(src+24);
            *reinterpret_cast<u16x8*>(&vLDS[t][0])  = v0;
            *reinterpret_cast<u16x8*>(&vLDS[t][8])  = v1;
            *reinterpret_cast<u16x8*>(&vLDS[t][16]) = v2;
            *reinterpret_cast<u16x8*>(&vLDS[t][24]) = v3;
        }

        // Phase A
        {
            float4 p0 = *reinterpret_cast<const float4*>(&skbase[(size_t)(jb+jj)*HH]);
            float4 p1 = *reinterpret_cast<const float4*>(&skbase[(size_t)(jb+jj)*HH+4]);
            float4 q0 = *reinterpret_cast<const float4*>(&skbase[(size_t)(jb+jj+1)*HH]);
            float4 q1 = *reinterpret_cast<const float4*>(&skbase[(size_t)(jb+jj+1)*HH+4]);
            unsigned wA = mArow[jt];
            unsigned wB = mBrow[jt];
            float ska[8] = {p0.x,p0.y,p0.z,p0.w,p1.x,p1.y,p1.z,p1.w};
            float skb[8] = {q0.x,q0.y,q0.z,q0.w,q1.x,q1.y,q1.z,q1.w};
            unsigned bA = (wA >> jj) & 3u;
            unsigned bB = (wB >> jj) & 3u;
            f32x2 wsA = {0.f,0.f}, wsB = {0.f,0.f};
            #pragma unroll
            for(int h=0; h<HH; h++){
                float eA0 = exp2f(lky(sq1[h]+ska[h]) - M1[h]);
                float eA1 = exp2f(lky(sq1[h]+skb[h]) - M1[h]);
                float eB0 = exp2f(lky(sq2[h]+ska[h]) - M2[h]);
                float eB1 = exp2f(lky(sq2[h]+skb[h]) - M2[h]);
                float w00 = (bA&1u) ? eA0 : 0.f;
                float w01 = (bA&2u) ? eA1 : 0.f;
                float w10 = (bB&1u) ? eB0 : 0.f;
                float w11 = (bB&2u) ? eB1 : 0.f;
                wsA += (f32x2){w00, w01};
                wsB += (f32x2){w10, w11};
                *reinterpret_cast<unsigned*>(&wLDS[h][ia][jj])    = cvtpk(w00, w01);
                *reinterpret_cast<unsigned*>(&wLDS[h][16+ia][jj]) = cvtpk(w10, w11);
            }
            wsA *= 0.125f; wsB *= 0.125f;
            *reinterpret_cast<f32x2*>(&meanw[((size_t)(R0+ia))*NN + jb + jj])    = wsA;
            *reinterpret_cast<f32x2*>(&meanw[((size_t)(R0+16+ia))*NN + jb + jj]) = wsB;
        }
        __syncthreads();

        // Phase B: MFMA
        #pragma unroll
        for(int hh=0; hh<2; hh++){
            int h = wid*2 + hh;
            bf16x8 a0 = *reinterpret_cast<const bf16x8*>(&wLDS[h][lr][kg*8]);
            bf16x8 a1 = *reinterpret_cast<const bf16x8*>(&wLDS[h][16+lr][kg*8]);
            bf16x8 b0 = *reinterpret_cast<const bf16x8*>(&vLDS[h*HD + lr][kg*8]);
            bf16x8 b1 = *reinterpret_cast<const bf16x8*>(&vLDS[h*HD + 16 + lr][kg*8]);
            acc[hh][0][0] = __builtin_amdgcn_mfma_f32_16x16x32_bf16(a0, b0, acc[hh][0][0], 0,0,0);
            acc[hh][0][1] = __builtin_amdgcn_mfma_f32_16x16x32_bf16(a0, b1, acc[hh][0][1], 0,0,0);
            acc[hh][1][0] = __builtin_amdgcn_mfma_f32_16x16x32_bf16(a1, b0, acc[hh][1][0], 0,0,0);
            acc[hh][1][1] = __builtin_amdgcn_mfma_f32_16x16x32_bf16(a1, b1, acc[hh][1][1], 0,0,0);
        }
    }

    // Epilogue: XOR-swizzled fb, coalesced bf16 stores
    __syncthreads();
    #pragma unroll
    for(int hh=0;hh<2;hh++)
        #pragma unroll
        for(int mi=0;mi<2;mi++)
            #pragma unroll
            for(int ni=0;ni<2;ni++)
                #pragma unroll
                for(int rg=0; rg<4; rg++){
                    int i = mi*16 + kg*4 + rg;
                    int d = (wid*2+hh)*HD + ni*16 + lr;
                    fb[i*256 + (d ^ ((i&7)<<2))] = acc[hh][mi][ni][rg];
                }
    __syncthreads();
    {
        int i  = t >> 3;              // 0..31 row; 8 threads per row
        int d0 = (t & 7) * 32;        // contiguous 512B per row across 8 threads
        int swz = (i & 7) << 2;
        size_t orow = ((size_t)(jc*BB + b)*NN + i0 + i)*DD + d0;
        #pragma unroll
        for(int qq=0; qq<4; qq++){
            float4 f0 = *reinterpret_cast<const float4*>(&fb[i*256 + ((d0 + qq*8)     ^ swz)]);
            float4 f1 = *reinterpret_cast<const float4*>(&fb[i*256 + ((d0 + qq*8 + 4) ^ swz)]);
            uint4 pk;
            pk.x = cvtpk(f0.x, f0.y); pk.y = cvtpk(f0.z, f0.w);
            pk.z = cvtpk(f1.x, f1.y); pk.w = cvtpk(f1.z, f1.w);
            *reinterpret_cast<uint4*>(&attp[orow + qq*8]) = pk;
        }
    }
}

// K4: out = LN( (sum attp) @ Wo + bo + x ) — MFMA GEMM, 16 REAL rows/block (no zero pad).
__global__ __launch_bounds__(256, 2)
void k_out(const ushort* __restrict__ attp, const float* __restrict__ x,
           const ushort* __restrict__ WoT, const float* __restrict__ bo,
           const float* __restrict__ g, const float* __restrict__ bln,
           float* __restrict__ out){
    __shared__ ushort ab[16][264];   // bf16 attended, 16 real rows
    __shared__ float fbo[16][260];   // GEMM result / LN scratch
    __shared__ float ps[16][16][2];
    __shared__ float muL[16], rsL[16];
    int t = threadIdx.x;
    int r0 = blockIdx.x*16;
    int b  = r0 >> 11;
    int j0 = r0 & (NN-1);

    // sum partials -> ab bf16 (two row-groups of 8)
    #pragma unroll
    for(int rp=0; rp<2; rp++){
        int rr = rp*8 + (t >> 5);
        int d0 = (t & 31) * 8;
        float s8[8];
        #pragma unroll
        for(int e=0;e<8;e++) s8[e]=0.f;
        #pragma unroll
        for(int jc=0; jc<JC; jc++){
            u16x8 v = *reinterpret_cast<const u16x8*>(&attp[((size_t)(jc*BB + b)*NN + j0 + rr)*DD + d0]);
            #pragma unroll
            for(int e=0;e<8;e++) s8[e] += bf2f(v[e]);
        }
        u16x8 pack;
        #pragma unroll
        for(int e=0;e<8;e++) pack[e] = f2bf(s8[e]);
        *reinterpret_cast<u16x8*>(&ab[rr][d0]) = pack;
    }
    __syncthreads();

    // MFMA GEMM: wave wv handles n-tiles 4wv..4wv+3, M=16 all-real
    {
        int wv = t>>6, l = t&63, lr = l&15, kg = l>>4;
        f32x4 acc0 = (f32x4){0.f,0.f,0.f,0.f};
        f32x4 acc1 = (f32x4){0.f,0.f,0.f,0.f};
        f32x4 acc2 = (f32x4){0.f,0.f,0.f,0.f};
        f32x4 acc3 = (f32x4){0.f,0.f,0.f,0.f};
        #pragma unroll
        for(int ks=0; ks<8; ks++){
            bf16x8 a = *reinterpret_cast<const bf16x8*>(&ab[lr][ks*32 + kg*8]);
            bf16x8 b0 = *reinterpret_cast<const bf16x8*>(WoT + (size_t)((wv*4+0)*16 + lr)*DD + ks*32 + kg*8);
            bf16x8 b1 = *reinterpret_cast<const bf16x8*>(WoT + (size_t)((wv*4+1)*16 + lr)*DD + ks*32 + kg*8);
            bf16x8 b2 = *reinterpret_cast<const bf16x8*>(WoT + (size_t)((wv*4+2)*16 + lr)*DD + ks*32 + kg*8);
            bf16x8 b3 = *reinterpret_cast<const bf16x8*>(WoT + (size_t)((wv*4+3)*16 + lr)*DD + ks*32 + kg*8);
            acc0 = __builtin_amdgcn_mfma_f32_16x16x32_bf16(a, b0, acc0, 0,0,0);
            acc1 = __builtin_amdgcn_mfma_f32_16x16x32_bf16(a, b1, acc1, 0,0,0);
            acc2 = __builtin_amdgcn_mfma_f32_16x16x32_bf16(a, b2, acc2, 0,0,0);
            acc3 = __builtin_amdgcn_mfma_f32_16x16x32_bf16(a, b3, acc3, 0,0,0);
        }
        #pragma unroll
        for(int rg=0; rg<4; rg++){
            int i = kg*4 + rg;
            fbo[i][(wv*4+0)*16 + lr] = acc0[rg];
            fbo[i][(wv*4+1)*16 + lr] = acc1[rg];
            fbo[i][(wv*4+2)*16 + lr] = acc2[rg];
            fbo[i][(wv*4+3)*16 + lr] = acc3[rg];
        }
    }
    __syncthreads();

    // residual + LN (thread t = col)
    float accr[16];
    float bb = bo[t];
    #pragma unroll
    for(int r=0;r<16;r++) accr[r] = fbo[r][t] + bb + x[((size_t)r0+r)*DD + t];
    __syncthreads();
    #pragma unroll
    for(int r=0;r<16;r++) fbo[r][t] = accr[r];
    __syncthreads();
    {
        int rr = t>>4, seg = t&15;
        float s=0.f, sqs=0.f;
        #pragma unroll
        for(int e=0;e<16;e++){
            float y = fbo[rr][seg*16+e];
            s += y; sqs += y*y;
        }
        ps[rr][seg][0]=s; ps[rr][seg][1]=sqs;
    }
    __syncthreads();
    if(t<16){
        float s=0.f, sqs=0.f;
        #pragma unroll
        for(int e=0;e<16;e++){ s+=ps[t][e][0]; sqs+=ps[t][e][1]; }
        float mu = s/256.f;
        float var = sqs/256.f - mu*mu;
        muL[t]=mu; rsL[t]=rsqrtf(var+EPS);
    }
    __syncthreads();
    float gg = g[t], bl = bln[t];
    #pragma unroll
    for(int r=0;r<16;r++){
        out[((size_t)r0+r)*DD + t] = (accr[r]-muL[r])*rsL[r]*gg + bl;
    }
}

extern "C" void kernel_launch(void* const* d_in, const int* in_sizes, int n_in,
                              void* d_out, int out_size, void* d_ws, size_t ws_size,
                              hipStream_t stream) {
    const float* x    = (const float*)d_in[0];
    const int*   adj  = (const int*)d_in[1];
    const float* Wq   = (const float*)d_in[2];
    const float* bq   = (const float*)d_in[3];
    const float* Wk   = (const float*)d_in[4];
    const float* bk   = (const float*)d_in[5];
    const float* Wv   = (const float*)d_in[6];
    const float* bv   = (const float*)d_in[7];
    const float* aa   = (const float*)d_in[8];
    const float* Wo   = (const float*)d_in[9];
    const float* bo   = (const float*)d_in[10];
    const float* lng  = (const float*)d_in[11];
    const float* lnb  = (const float*)d_in[12];

    float* out0  = (float*)d_out;                  // (B,N,D)
    float* meanw = out0 + (size_t)BB*NN*DD;        // (B,N,N)

    char* wsb = (char*)d_ws;
    float* cq   = (float*)wsb;                                    // 16
    float* ck   = cq + 16;                                        // 16
    float* Mk   = ck + 16;                                        // 16 (+pad)
    float* sqv  = Mk + 80;                                        // 32768
    float* skH  = sqv + 32768;                                    // 32768
    float* Madj = skH + 32768;                                    // 32768
    unsigned* adjm = (unsigned*)(Madj + 32768);                   // BB*NN*64 u32 = 1MB
    ushort* uqkb= (ushort*)(adjm + (size_t)BB*NN*64);             // 16*256 u16
    ushort* WoT = uqkb + 16*DD;                                   // 256*256 u16
    ushort* vT  = WoT + (size_t)DD*DD;                            // BB*DD*NN u16
    ushort* attp= vT + (size_t)BB*DD*NN;                          // JC*BB*NN*DD u16

    k_prep<<<72, 256, 0, stream>>>(Wq, bq, Wk, bk, aa, Wo, uqkb, cq, ck, WoT);
    k_sqskv<<<(BB*NN)/8, 256, 0, stream>>>(x, Wv, bv, uqkb, cq, ck, vT, sqv, skH);
    k_maxsk<<<BB*HH, 256, 0, stream>>>(skH, Mk);
    k_denom<<<(BB*NN)/2, 256, 0, stream>>>(adj, sqv, skH, Mk, Madj, adjm);
    k_attn<<<dim3(NN/TI, BB, JC), 256, 0, stream>>>(adjm, sqv, skH, Madj, vT, meanw, attp);
    k_out<<<(BB*NN)/16, 256, 0, stream>>>(attp, x, WoT, bo, lng, lnb, out0);
}

// Round 18
// 101.458 us; speedup vs baseline: 2.7524x; 1.1627x over previous
//
#include <hip/hip_runtime.h>

#define BB 2
#define NN 2048
#define DD 256
#define HH 8
#define HD 32
#define EPS 1e-5f
#define L2E 1.4426950408889634f

typedef __attribute__((ext_vector_type(8))) short bf16x8;
typedef __attribute__((ext_vector_type(4))) float f32x4;
typedef __attribute__((ext_vector_type(2))) float f32x2;
typedef __attribute__((ext_vector_type(8))) unsigned short u16x8;

__device__ __forceinline__ float lky(float z){ return fmaxf(z, 0.2f*z); }

__device__ __forceinline__ ushort f2bf(float f){
    union{ float f; unsigned u; } c; c.f = f;
    unsigned r = c.u + 0x7fffu + ((c.u >> 16) & 1u);
    return (ushort)(r >> 16);
}
__device__ __forceinline__ float bf2f(ushort u){
    union{ unsigned u; float f; } c; c.u = ((unsigned)u) << 16; return c.f;
}
__device__ __forceinline__ unsigned cvtpk(float lo, float hi){
    unsigned r;
    asm("v_cvt_pk_bf16_f32 %0, %1, %2" : "=v"(r) : "v"(lo), "v"(hi));
    return r;
}

// K0: blocks 0-7: uqkb bf16 + cq/ck (log2e-scaled); 8-71: WoT; 72-135: WvT.
__global__ void k_prep(const float* __restrict__ Wq, const float* __restrict__ bq,
                       const float* __restrict__ Wk, const float* __restrict__ bk,
                       const float* __restrict__ aa, const float* __restrict__ Wo,
                       const float* __restrict__ Wv,
                       ushort* __restrict__ uqkb, float* __restrict__ cq,
                       float* __restrict__ ck, ushort* __restrict__ WoT,
                       ushort* __restrict__ WvT){
    int t = threadIdx.x;
    if(blockIdx.x < 8){
        int h = blockIdx.x;
        int d = t;
        float accq = 0.f, acck = 0.f;
        #pragma unroll
        for(int k=0; k<HD; k++){
            accq += Wq[(size_t)d*DD + h*HD + k] * aa[h*2*HD + k];
            acck += Wk[(size_t)d*DD + h*HD + k] * aa[h*2*HD + HD + k];
        }
        uqkb[h*DD + d]     = f2bf(accq * L2E);
        uqkb[(8+h)*DD + d] = f2bf(acck * L2E);
        __shared__ float red[64];
        if(d < HD){
            red[d]      = bq[h*HD+d]*aa[h*2*HD+d];
            red[32+d]   = bk[h*HD+d]*aa[h*2*HD+HD+d];
        }
        __syncthreads();
        if(d==0){ float s=0.f; for(int k=0;k<32;k++) s+=red[k];    cq[h]=s*L2E; }
        if(d==1){ float s=0.f; for(int k=0;k<32;k++) s+=red[32+k]; ck[h]=s*L2E; }
    } else if(blockIdx.x < 72){
        int blk = blockIdx.x - 8;     // 0..63
        int wv = t>>6, l = t&63;
        int tile = blk*4 + wv;        // 0..255
        int tr = (tile>>4)*16, tc = (tile&15)*16;
        #pragma unroll
        for(int e=0;e<4;e++){
            int idx = l*4+e;
            int kk = tr + (idx>>4);
            int nn = tc + (idx&15);
            WoT[(size_t)nn*DD + kk] = f2bf(Wo[(size_t)kk*DD + nn]);
        }
    } else {
        int blk = blockIdx.x - 72;    // 0..63
        int wv = t>>6, l = t&63;
        int tile = blk*4 + wv;
        int tr = (tile>>4)*16, tc = (tile&15)*16;
        #pragma unroll
        for(int e=0;e<4;e++){
            int idx = l*4+e;
            int kk = tr + (idx>>4);
            int nn = tc + (idx&15);
            WvT[(size_t)nn*DD + kk] = f2bf(Wv[(size_t)kk*DD + nn]);
        }
    }
}

// K1: 16 rows/block, full MFMA: scores (wave0) + v-projection GEMM (all waves).
__global__ __launch_bounds__(256, 4)
void k_sqskv(const float* __restrict__ x, const float* __restrict__ bv,
             const ushort* __restrict__ uqkb, const ushort* __restrict__ WvT,
             const float* __restrict__ cq, const float* __restrict__ ck,
             ushort* __restrict__ vT, float* __restrict__ sq,
             float* __restrict__ skH){
    __shared__ ushort xb[16][264];   // bf16 x rows
    int t = threadIdx.x;
    int r0 = blockIdx.x * 16;
    int b  = r0 >> 11;
    int j0 = r0 & (NN-1);
    #pragma unroll
    for(int i=0;i<16;i++) xb[i][t] = f2bf(x[((size_t)r0+i)*DD + t]);
    __syncthreads();

    int wv = t>>6, l = t&63, lr = l&15, kg = l>>4;

    // wave 0: scores: C[i][n] = sum_k xb[i][k]*uqkb[n][k]  (M=16 real rows)
    if(wv == 0){
        f32x4 acc = (f32x4){0.f,0.f,0.f,0.f};
        #pragma unroll
        for(int ks=0; ks<8; ks++){
            bf16x8 a = *reinterpret_cast<const bf16x8*>(&xb[lr][ks*32 + kg*8]);
            bf16x8 bb = *reinterpret_cast<const bf16x8*>(uqkb + (size_t)lr*DD + ks*32 + kg*8);
            acc = __builtin_amdgcn_mfma_f32_16x16x32_bf16(a, bb, acc, 0,0,0);
        }
        #pragma unroll
        for(int rg=0; rg<4; rg++){
            int i = kg*4 + rg;
            int R = r0 + i;
            float vsc = acc[rg];
            if(lr < 8) sq[(size_t)R*HH + lr] = vsc + cq[lr];
            else       skH[((size_t)b*NN + (R & (NN-1)))*HH + (lr-8)] = vsc + ck[lr-8];
        }
    }

    // v GEMM: wave wv -> n-tiles 4wv..4wv+3; C[i][n]; store vT[b][n][j0+i]
    f32x4 vacc[4];
    #pragma unroll
    for(int q=0;q<4;q++) vacc[q] = (f32x4){0.f,0.f,0.f,0.f};
    #pragma unroll
    for(int ks=0; ks<8; ks++){
        bf16x8 a = *reinterpret_cast<const bf16x8*>(&xb[lr][ks*32 + kg*8]);
        #pragma unroll
        for(int q=0;q<4;q++){
            int n0 = (wv*4+q)*16;
            bf16x8 bb = *reinterpret_cast<const bf16x8*>(WvT + (size_t)(n0+lr)*DD + ks*32 + kg*8);
            vacc[q] = __builtin_amdgcn_mfma_f32_16x16x32_bf16(a, bb, vacc[q], 0,0,0);
        }
    }
    #pragma unroll
    for(int q=0;q<4;q++){
        int n = (wv*4+q)*16 + lr;
        float bvn = bv[n];
        ushort4 pk;
        pk.x = f2bf(vacc[q][0] + bvn);
        pk.y = f2bf(vacc[q][1] + bvn);
        pk.z = f2bf(vacc[q][2] + bvn);
        pk.w = f2bf(vacc[q][3] + bvn);
        *reinterpret_cast<ushort4*>(&vT[((size_t)b*DD + n)*NN + j0 + kg*4]) = pk;
    }
}

// K1b: Mk[b][h] = max_j skH[b][j][h]
__global__ void k_maxsk(const float* __restrict__ skH, float* __restrict__ Mk){
    int b = blockIdx.x >> 3, h = blockIdx.x & 7;
    int t = threadIdx.x;
    float m = -1e30f;
    for(int j=t; j<NN; j+=256) m = fmaxf(m, skH[((size_t)b*NN + j)*HH + h]);
    #pragma unroll
    for(int off=32; off>=1; off>>=1) m = fmaxf(m, __shfl_xor(m, off));
    __shared__ float red[4];
    if((t&63)==0) red[t>>6] = m;
    __syncthreads();
    if(t==0) Mk[blockIdx.x] = fmaxf(fmaxf(red[0],red[1]), fmaxf(red[2],red[3]));
}

// K2: 2 rows/block, raw adj in, Madj + adj-bitmask out (pack free — adj already read here)
__global__ void k_denom(const int* __restrict__ adj, const float* __restrict__ sq,
                        const float* __restrict__ skH, const float* __restrict__ Mk,
                        float* __restrict__ Madj, unsigned* __restrict__ adjm){
    int r0 = blockIdx.x*2;          // rows r0, r0+1 (same b)
    int b = r0 >> 11;
    int t = threadIdx.x;
    int w = t>>6, l = t&63;
    float sq1[HH], sq2[HH], M1[HH], M2[HH], s1[HH], s2[HH];
    {
        float4 a0 = *reinterpret_cast<const float4*>(&sq[(size_t)r0*HH]);
        float4 a1 = *reinterpret_cast<const float4*>(&sq[(size_t)r0*HH+4]);
        float4 b0 = *reinterpret_cast<const float4*>(&sq[(size_t)(r0+1)*HH]);
        float4 b1 = *reinterpret_cast<const float4*>(&sq[(size_t)(r0+1)*HH+4]);
        float4 m0 = *reinterpret_cast<const float4*>(&Mk[b*HH]);
        float4 m1 = *reinterpret_cast<const float4*>(&Mk[b*HH+4]);
        sq1[0]=a0.x; sq1[1]=a0.y; sq1[2]=a0.z; sq1[3]=a0.w;
        sq1[4]=a1.x; sq1[5]=a1.y; sq1[6]=a1.z; sq1[7]=a1.w;
        sq2[0]=b0.x; sq2[1]=b0.y; sq2[2]=b0.z; sq2[3]=b0.w;
        sq2[4]=b1.x; sq2[5]=b1.y; sq2[6]=b1.z; sq2[7]=b1.w;
        float mk[8] = {m0.x,m0.y,m0.z,m0.w,m1.x,m1.y,m1.z,m1.w};
        #pragma unroll
        for(int h=0;h<HH;h++){
            M1[h] = lky(sq1[h]+mk[h]); M2[h] = lky(sq2[h]+mk[h]);
            s1[h]=0.f; s2[h]=0.f;
        }
    }
    const int* arow1 = adj + (size_t)r0*NN;
    const int* arow2 = adj + ((size_t)r0+1)*NN;
    for(int j0=0; j0<NN; j0+=256){
        int j = j0 + t;
        int a1 = arow1[j];
        int a2 = arow2[j];
        {
            unsigned long long m1b = __ballot(a1 != 0);
            unsigned long long m2b = __ballot(a2 != 0);
            int cw = (j0 >> 5) + w*2;
            if(l == 0){
                adjm[(size_t)r0*64 + cw]       = (unsigned)m1b;
                adjm[((size_t)r0+1)*64 + cw]   = (unsigned)m2b;
            }
            if(l == 32){
                adjm[(size_t)r0*64 + cw + 1]     = (unsigned)(m1b >> 32);
                adjm[((size_t)r0+1)*64 + cw + 1] = (unsigned)(m2b >> 32);
            }
        }
        float4 v0 = *reinterpret_cast<const float4*>(&skH[((size_t)b*NN + j)*HH]);
        float4 v1 = *reinterpret_cast<const float4*>(&skH[((size_t)b*NN + j)*HH+4]);
        float sk[8] = {v0.x,v0.y,v0.z,v0.w,v1.x,v1.y,v1.z,v1.w};
        #pragma unroll
        for(int h=0; h<HH; h++){
            float e1 = exp2f(lky(sq1[h]+sk[h]) - M1[h]);
            float e2 = exp2f(lky(sq2[h]+sk[h]) - M2[h]);
            s1[h] += a1 ? e1 : 0.f;
            s2[h] += a2 ? e2 : 0.f;
        }
    }
    #pragma unroll
    for(int h=0;h<HH;h++){
        #pragma unroll
        for(int off=32; off>=1; off>>=1){
            s1[h] += __shfl_xor(s1[h], off);
            s2[h] += __shfl_xor(s2[h], off);
        }
    }
    __shared__ float red[4][16];
    if(l==0){
        #pragma unroll
        for(int h=0;h<HH;h++){ red[w][h]=s1[h]; red[w][8+h]=s2[h]; }
    }
    __syncthreads();
    if(t < 16){
        float s = red[0][t]+red[1][t]+red[2][t]+red[3][t];
        int h = t & 7;
        if(t < 8) Madj[(size_t)r0*HH + h]     = M1[h] + log2f(s);
        else      Madj[((size_t)r0+1)*HH + h] = M2[h] + log2f(s);
    }
}

// K3 (R13/R15/R17 verified variant): adjm bitmask, loads after barrier, XOR-swizzled epilogue.
#define TI 32
#define JT 32
#define JC 8
#define JPC (NN/JC)   // 256

__global__ __launch_bounds__(256, 4)
void k_attn(const unsigned* __restrict__ adjm, const float* __restrict__ sq,
            const float* __restrict__ skH, const float* __restrict__ Madj,
            const ushort* __restrict__ vT, float* __restrict__ meanw,
            ushort* __restrict__ attp){
    __shared__ __align__(16) char smem[40960];
    ushort (*wLDS)[TI][40] = (ushort (*)[TI][40])smem;           // [h][i][j] 20480B
    ushort (*vLDS)[40]     = (ushort (*)[40])(smem + 20480);     // [d][j]    20480B
    float* fb = (float*)smem;                                     // epilogue 32KB

    int t  = threadIdx.x;
    int it = blockIdx.x;
    int b  = blockIdx.y;
    int jc = blockIdx.z;
    int i0 = it*TI;
    int R0 = b*NN + i0;

    int ia = t >> 4;
    int jp = t & 15;
    int jj = jp*2;

    float sq1[8], sq2[8], M1[8], M2[8];
    {
        float4 a0 = *reinterpret_cast<const float4*>(&sq[(size_t)(R0+ia)*HH]);
        float4 a1 = *reinterpret_cast<const float4*>(&sq[(size_t)(R0+ia)*HH+4]);
        float4 b0 = *reinterpret_cast<const float4*>(&sq[(size_t)(R0+16+ia)*HH]);
        float4 b1 = *reinterpret_cast<const float4*>(&sq[(size_t)(R0+16+ia)*HH+4]);
        sq1[0]=a0.x; sq1[1]=a0.y; sq1[2]=a0.z; sq1[3]=a0.w;
        sq1[4]=a1.x; sq1[5]=a1.y; sq1[6]=a1.z; sq1[7]=a1.w;
        sq2[0]=b0.x; sq2[1]=b0.y; sq2[2]=b0.z; sq2[3]=b0.w;
        sq2[4]=b1.x; sq2[5]=b1.y; sq2[6]=b1.z; sq2[7]=b1.w;
        float4 c0 = *reinterpret_cast<const float4*>(&Madj[(size_t)(R0+ia)*HH]);
        float4 c1 = *reinterpret_cast<const float4*>(&Madj[(size_t)(R0+ia)*HH+4]);
        float4 d0 = *reinterpret_cast<const float4*>(&Madj[(size_t)(R0+16+ia)*HH]);
        float4 d1 = *reinterpret_cast<const float4*>(&Madj[(size_t)(R0+16+ia)*HH+4]);
        M1[0]=c0.x; M1[1]=c0.y; M1[2]=c0.z; M1[3]=c0.w;
        M1[4]=c1.x; M1[5]=c1.y; M1[6]=c1.z; M1[7]=c1.w;
        M2[0]=d0.x; M2[1]=d0.y; M2[2]=d0.z; M2[3]=d0.w;
        M2[4]=d1.x; M2[5]=d1.y; M2[6]=d1.z; M2[7]=d1.w;
    }

    int wid = t >> 6;
    int l   = t & 63;
    int lr  = l & 15;
    int kg  = l >> 4;

    f32x4 acc[2][2][2];
    #pragma unroll
    for(int hh=0;hh<2;hh++)
        #pragma unroll
        for(int mi=0;mi<2;mi++)
            #pragma unroll
            for(int ni=0;ni<2;ni++) acc[hh][mi][ni] = (f32x4){0.f,0.f,0.f,0.f};

    const ushort* vsrc = vT + ((size_t)b*DD + t)*NN;
    const float* skbase = skH + (size_t)b*NN*HH;
    const unsigned* mArow = adjm + (size_t)(R0+ia)*64 + jc*8;
    const unsigned* mBrow = adjm + (size_t)(R0+16+ia)*64 + jc*8;

    for(int jt=0; jt<JPC/JT; jt++){
        int jb = jc*JPC + jt*JT;

        __syncthreads();   // prev tile MFMA done reading wLDS/vLDS

        // stage v to LDS (loads AFTER barrier — proven placement)
        {
            const ushort* src = vsrc + jb;
            u16x8 v0 = *reinterpret_cast<const u16x8*>(src);
            u16x8 v1 = *reinterpret_cast<const u16x8*>(src+8);
            u16x8 v2 = *reinterpret_cast<const u16x8*>(src+16);
            u16x8 v3 = *reinterpret_cast<const u16x8*>(src+24);
            *reinterpret_cast<u16x8*>(&vLDS[t][0])  = v0;
            *reinterpret_cast<u16x8*>(&vLDS[t][8])  = v1;
            *reinterpret_cast<u16x8*>(&vLDS[t][16]) = v2;
            *reinterpret_cast<u16x8*>(&vLDS[t][24]) = v3;
        }

        // Phase A
        {
            float4 p0 = *reinterpret_cast<const float4*>(&skbase[(size_t)(jb+jj)*HH]);
            float4 p1 = *reinterpret_cast<const float4*>(&skbase[(size_t)(jb+jj)*HH+4]);
            float4 q0 = *reinterpret_cast<const float4*>(&skbase[(size_t)(jb+jj+1)*HH]);
            float4 q1 = *reinterpret_cast<const float4*>(&skbase[(size_t)(jb+jj+1)*HH+4]);
            unsigned wA = mArow[jt];
            unsigned wB = mBrow[jt];
            float ska[8] = {p0.x,p0.y,p0.z,p0.w,p1.x,p1.y,p1.z,p1.w};
            float skb[8] = {q0.x,q0.y,q0.z,q0.w,q1.x,q1.y,q1.z,q1.w};
            unsigned bA = (wA >> jj) & 3u;
            unsigned bB = (wB >> jj) & 3u;
            f32x2 wsA = {0.f,0.f}, wsB = {0.f,0.f};
            #pragma unroll
            for(int h=0; h<HH; h++){
                float eA0 = exp2f(lky(sq1[h]+ska[h]) - M1[h]);
                float eA1 = exp2f(lky(sq1[h]+skb[h]) - M1[h]);
                float eB0 = exp2f(lky(sq2[h]+ska[h]) - M2[h]);
                float eB1 = exp2f(lky(sq2[h]+skb[h]) - M2[h]);
                float w00 = (bA&1u) ? eA0 : 0.f;
                float w01 = (bA&2u) ? eA1 : 0.f;
                float w10 = (bB&1u) ? eB0 : 0.f;
                float w11 = (bB&2u) ? eB1 : 0.f;
                wsA += (f32x2){w00, w01};
                wsB += (f32x2){w10, w11};
                *reinterpret_cast<unsigned*>(&wLDS[h][ia][jj])    = cvtpk(w00, w01);
                *reinterpret_cast<unsigned*>(&wLDS[h][16+ia][jj]) = cvtpk(w10, w11);
            }
            wsA *= 0.125f; wsB *= 0.125f;
            *reinterpret_cast<f32x2*>(&meanw[((size_t)(R0+ia))*NN + jb + jj])    = wsA;
            *reinterpret_cast<f32x2*>(&meanw[((size_t)(R0+16+ia))*NN + jb + jj]) = wsB;
        }
        __syncthreads();

        // Phase B: MFMA
        #pragma unroll
        for(int hh=0; hh<2; hh++){
            int h = wid*2 + hh;
            bf16x8 a0 = *reinterpret_cast<const bf16x8*>(&wLDS[h][lr][kg*8]);
            bf16x8 a1 = *reinterpret_cast<const bf16x8*>(&wLDS[h][16+lr][kg*8]);
            bf16x8 b0 = *reinterpret_cast<const bf16x8*>(&vLDS[h*HD + lr][kg*8]);
            bf16x8 b1 = *reinterpret_cast<const bf16x8*>(&vLDS[h*HD + 16 + lr][kg*8]);
            acc[hh][0][0] = __builtin_amdgcn_mfma_f32_16x16x32_bf16(a0, b0, acc[hh][0][0], 0,0,0);
            acc[hh][0][1] = __builtin_amdgcn_mfma_f32_16x16x32_bf16(a0, b1, acc[hh][0][1], 0,0,0);
            acc[hh][1][0] = __builtin_amdgcn_mfma_f32_16x16x32_bf16(a1, b0, acc[hh][1][0], 0,0,0);
            acc[hh][1][1] = __builtin_amdgcn_mfma_f32_16x16x32_bf16(a1, b1, acc[hh][1][1], 0,0,0);
        }
    }

    // Epilogue: XOR-swizzled fb, coalesced bf16 stores
    __syncthreads();
    #pragma unroll
    for(int hh=0;hh<2;hh++)
        #pragma unroll
        for(int mi=0;mi<2;mi++)
            #pragma unroll
            for(int ni=0;ni<2;ni++)
                #pragma unroll
                for(int rg=0; rg<4; rg++){
                    int i = mi*16 + kg*4 + rg;
                    int d = (wid*2+hh)*HD + ni*16 + lr;
                    fb[i*256 + (d ^ ((i&7)<<2))] = acc[hh][mi][ni][rg];
                }
    __syncthreads();
    {
        int i  = t >> 3;              // 0..31 row; 8 threads per row
        int d0 = (t & 7) * 32;        // contiguous 512B per row across 8 threads
        int swz = (i & 7) << 2;
        size_t orow = ((size_t)(jc*BB + b)*NN + i0 + i)*DD + d0;
        #pragma unroll
        for(int qq=0; qq<4; qq++){
            float4 f0 = *reinterpret_cast<const float4*>(&fb[i*256 + ((d0 + qq*8)     ^ swz)]);
            float4 f1 = *reinterpret_cast<const float4*>(&fb[i*256 + ((d0 + qq*8 + 4) ^ swz)]);
            uint4 pk;
            pk.x = cvtpk(f0.x, f0.y); pk.y = cvtpk(f0.z, f0.w);
            pk.z = cvtpk(f1.x, f1.y); pk.w = cvtpk(f1.z, f1.w);
            *reinterpret_cast<uint4*>(&attp[orow + qq*8]) = pk;
        }
    }
}

// K4: out = LN( (sum attp) @ Wo + bo + x ) — MFMA GEMM, 16 real rows/block.
__global__ __launch_bounds__(256, 2)
void k_out(const ushort* __restrict__ attp, const float* __restrict__ x,
           const ushort* __restrict__ WoT, const float* __restrict__ bo,
           const float* __restrict__ g, const float* __restrict__ bln,
           float* __restrict__ out){
    __shared__ ushort ab[16][264];   // bf16 attended, 16 real rows
    __shared__ float fbo[16][260];   // GEMM result / LN scratch
    __shared__ float ps[16][16][2];
    __shared__ float muL[16], rsL[16];
    int t = threadIdx.x;
    int r0 = blockIdx.x*16;
    int b  = r0 >> 11;
    int j0 = r0 & (NN-1);

    // sum partials -> ab bf16 (two row-groups of 8)
    #pragma unroll
    for(int rp=0; rp<2; rp++){
        int rr = rp*8 + (t >> 5);
        int d0 = (t & 31) * 8;
        float s8[8];
        #pragma unroll
        for(int e=0;e<8;e++) s8[e]=0.f;
        #pragma unroll
        for(int jc=0; jc<JC; jc++){
            u16x8 v = *reinterpret_cast<const u16x8*>(&attp[((size_t)(jc*BB + b)*NN + j0 + rr)*DD + d0]);
            #pragma unroll
            for(int e=0;e<8;e++) s8[e] += bf2f(v[e]);
        }
        u16x8 pack;
        #pragma unroll
        for(int e=0;e<8;e++) pack[e] = f2bf(s8[e]);
        *reinterpret_cast<u16x8*>(&ab[rr][d0]) = pack;
    }
    __syncthreads();

    // MFMA GEMM: wave wv handles n-tiles 4wv..4wv+3, M=16 all-real
    {
        int wv = t>>6, l = t&63, lr = l&15, kg = l>>4;
        f32x4 acc0 = (f32x4){0.f,0.f,0.f,0.f};
        f32x4 acc1 = (f32x4){0.f,0.f,0.f,0.f};
        f32x4 acc2 = (f32x4){0.f,0.f,0.f,0.f};
        f32x4 acc3 = (f32x4){0.f,0.f,0.f,0.f};
        #pragma unroll
        for(int ks=0; ks<8; ks++){
            bf16x8 a = *reinterpret_cast<const bf16x8*>(&ab[lr][ks*32 + kg*8]);
            bf16x8 b0 = *reinterpret_cast<const bf16x8*>(WoT + (size_t)((wv*4+0)*16 + lr)*DD + ks*32 + kg*8);
            bf16x8 b1 = *reinterpret_cast<const bf16x8*>(WoT + (size_t)((wv*4+1)*16 + lr)*DD + ks*32 + kg*8);
            bf16x8 b2 = *reinterpret_cast<const bf16x8*>(WoT + (size_t)((wv*4+2)*16 + lr)*DD + ks*32 + kg*8);
            bf16x8 b3 = *reinterpret_cast<const bf16x8*>(WoT + (size_t)((wv*4+3)*16 + lr)*DD + ks*32 + kg*8);
            acc0 = __builtin_amdgcn_mfma_f32_16x16x32_bf16(a, b0, acc0, 0,0,0);
            acc1 = __builtin_amdgcn_mfma_f32_16x16x32_bf16(a, b1, acc1, 0,0,0);
            acc2 = __builtin_amdgcn_mfma_f32_16x16x32_bf16(a, b2, acc2, 0,0,0);
            acc3 = __builtin_amdgcn_mfma_f32_16x16x32_bf16(a, b3, acc3, 0,0,0);
        }
        #pragma unroll
        for(int rg=0; rg<4; rg++){
            int i = kg*4 + rg;
            fbo[i][(wv*4+0)*16 + lr] = acc0[rg];
            fbo[i][(wv*4+1)*16 + lr] = acc1[rg];
            fbo[i][(wv*4+2)*16 + lr] = acc2[rg];
            fbo[i][(wv*4+3)*16 + lr] = acc3[rg];
        }
    }
    __syncthreads();

    // residual + LN (thread t = col)
    float accr[16];
    float bb = bo[t];
    #pragma unroll
    for(int r=0;r<16;r++) accr[r] = fbo[r][t] + bb + x[((size_t)r0+r)*DD + t];
    __syncthreads();
    #pragma unroll
    for(int r=0;r<16;r++) fbo[r][t] = accr[r];
    __syncthreads();
    {
        int rr = t>>4, seg = t&15;
        float s=0.f, sqs=0.f;
        #pragma unroll
        for(int e=0;e<16;e++){
            float y = fbo[rr][seg*16+e];
            s += y; sqs += y*y;
        }
        ps[rr][seg][0]=s; ps[rr][seg][1]=sqs;
    }
    __syncthreads();
    if(t<16){
        float s=0.f, sqs=0.f;
        #pragma unroll
        for(int e=0;e<16;e++){ s+=ps[t][e][0]; sqs+=ps[t][e][1]; }
        float mu = s/256.f;
        float var = sqs/256.f - mu*mu;
        muL[t]=mu; rsL[t]=rsqrtf(var+EPS);
    }
    __syncthreads();
    float gg = g[t], bl = bln[t];
    #pragma unroll
    for(int r=0;r<16;r++){
        out[((size_t)r0+r)*DD + t] = (accr[r]-muL[r])*rsL[r]*gg + bl;
    }
}

extern "C" void kernel_launch(void* const* d_in, const int* in_sizes, int n_in,
                              void* d_out, int out_size, void* d_ws, size_t ws_size,
                              hipStream_t stream) {
    const float* x    = (const float*)d_in[0];
    const int*   adj  = (const int*)d_in[1];
    const float* Wq   = (const float*)d_in[2];
    const float* bq   = (const float*)d_in[3];
    const float* Wk   = (const float*)d_in[4];
    const float* bk   = (const float*)d_in[5];
    const float* Wv   = (const float*)d_in[6];
    const float* bv   = (const float*)d_in[7];
    const float* aa   = (const float*)d_in[8];
    const float* Wo   = (const float*)d_in[9];
    const float* bo   = (const float*)d_in[10];
    const float* lng  = (const float*)d_in[11];
    const float* lnb  = (const float*)d_in[12];

    float* out0  = (float*)d_out;                  // (B,N,D)
    float* meanw = out0 + (size_t)BB*NN*DD;        // (B,N,N)

    char* wsb = (char*)d_ws;
    float* cq   = (float*)wsb;                                    // 16
    float* ck   = cq + 16;                                        // 16
    float* Mk   = ck + 16;                                        // 16 (+pad)
    float* sqv  = Mk + 80;                                        // 32768
    float* skH  = sqv + 32768;                                    // 32768
    float* Madj = skH + 32768;                                    // 32768
    unsigned* adjm = (unsigned*)(Madj + 32768);                   // BB*NN*64 u32 = 1MB
    ushort* uqkb= (ushort*)(adjm + (size_t)BB*NN*64);             // 16*256 u16
    ushort* WoT = uqkb + 16*DD;                                   // 256*256 u16
    ushort* WvT = WoT + (size_t)DD*DD;                            // 256*256 u16
    ushort* vT  = WvT + (size_t)DD*DD;                            // BB*DD*NN u16
    ushort* attp= vT + (size_t)BB*DD*NN;                          // JC*BB*NN*DD u16

    k_prep<<<136, 256, 0, stream>>>(Wq, bq, Wk, bk, aa, Wo, Wv, uqkb, cq, ck, WoT, WvT);
    k_sqskv<<<(BB*NN)/16, 256, 0, stream>>>(x, bv, uqkb, WvT, cq, ck, vT, sqv, skH);
    k_maxsk<<<BB*HH, 256, 0, stream>>>(skH, Mk);
    k_denom<<<(BB*NN)/2, 256, 0, stream>>>(adj, sqv, skH, Mk, Madj, adjm);
    k_attn<<<dim3(NN/TI, BB, JC), 256, 0, stream>>>(adjm, sqv, skH, Madj, vT, meanw, attp);
    k_out<<<(BB*NN)/16, 256, 0, stream>>>(attp, x, WoT, bo, lng, lnb, out0);
}

// Round 19
// 91.311 us; speedup vs baseline: 3.0582x; 1.1111x over previous
//
#include <hip/hip_runtime.h>

#define BB 2
#define NN 2048
#define DD 256
#define HH 8
#define HD 32
#define EPS 1e-5f
#define L2E 1.4426950408889634f

typedef __attribute__((ext_vector_type(8))) short bf16x8;
typedef __attribute__((ext_vector_type(4))) float f32x4;
typedef __attribute__((ext_vector_type(2))) float f32x2;
typedef __attribute__((ext_vector_type(8))) unsigned short u16x8;

__device__ __forceinline__ float lky(float z){ return fmaxf(z, 0.2f*z); }

// Raw hardware exp2: valid here because args <= ~0 and args < -126 must yield
// w ~= 0 (flush-to-zero is the correct answer). Avoids OCML's ~5-inst guard.
__device__ __forceinline__ float exp2raw(float x){
    float r;
    asm("v_exp_f32 %0, %1" : "=v"(r) : "v"(x));
    return r;
}

__device__ __forceinline__ ushort f2bf(float f){
    union{ float f; unsigned u; } c; c.f = f;
    unsigned r = c.u + 0x7fffu + ((c.u >> 16) & 1u);
    return (ushort)(r >> 16);
}
__device__ __forceinline__ float bf2f(ushort u){
    union{ unsigned u; float f; } c; c.u = ((unsigned)u) << 16; return c.f;
}
__device__ __forceinline__ unsigned cvtpk(float lo, float hi){
    unsigned r;
    asm("v_cvt_pk_bf16_f32 %0, %1, %2" : "=v"(r) : "v"(lo), "v"(hi));
    return r;
}

// K0: blocks 0-7: uqkb bf16 + cq/ck (log2e-scaled); 8-71: WoT; 72-135: WvT.
__global__ void k_prep(const float* __restrict__ Wq, const float* __restrict__ bq,
                       const float* __restrict__ Wk, const float* __restrict__ bk,
                       const float* __restrict__ aa, const float* __restrict__ Wo,
                       const float* __restrict__ Wv,
                       ushort* __restrict__ uqkb, float* __restrict__ cq,
                       float* __restrict__ ck, ushort* __restrict__ WoT,
                       ushort* __restrict__ WvT){
    int t = threadIdx.x;
    if(blockIdx.x < 8){
        int h = blockIdx.x;
        int d = t;
        float accq = 0.f, acck = 0.f;
        #pragma unroll
        for(int k=0; k<HD; k++){
            accq += Wq[(size_t)d*DD + h*HD + k] * aa[h*2*HD + k];
            acck += Wk[(size_t)d*DD + h*HD + k] * aa[h*2*HD + HD + k];
        }
        uqkb[h*DD + d]     = f2bf(accq * L2E);
        uqkb[(8+h)*DD + d] = f2bf(acck * L2E);
        __shared__ float red[64];
        if(d < HD){
            red[d]      = bq[h*HD+d]*aa[h*2*HD+d];
            red[32+d]   = bk[h*HD+d]*aa[h*2*HD+HD+d];
        }
        __syncthreads();
        if(d==0){ float s=0.f; for(int k=0;k<32;k++) s+=red[k];    cq[h]=s*L2E; }
        if(d==1){ float s=0.f; for(int k=0;k<32;k++) s+=red[32+k]; ck[h]=s*L2E; }
    } else if(blockIdx.x < 72){
        int blk = blockIdx.x - 8;     // 0..63
        int wv = t>>6, l = t&63;
        int tile = blk*4 + wv;        // 0..255
        int tr = (tile>>4)*16, tc = (tile&15)*16;
        #pragma unroll
        for(int e=0;e<4;e++){
            int idx = l*4+e;
            int kk = tr + (idx>>4);
            int nn = tc + (idx&15);
            WoT[(size_t)nn*DD + kk] = f2bf(Wo[(size_t)kk*DD + nn]);
        }
    } else {
        int blk = blockIdx.x - 72;    // 0..63
        int wv = t>>6, l = t&63;
        int tile = blk*4 + wv;
        int tr = (tile>>4)*16, tc = (tile&15)*16;
        #pragma unroll
        for(int e=0;e<4;e++){
            int idx = l*4+e;
            int kk = tr + (idx>>4);
            int nn = tc + (idx&15);
            WvT[(size_t)nn*DD + kk] = f2bf(Wv[(size_t)kk*DD + nn]);
        }
    }
}

// K1: 16 rows/block, full MFMA: scores (wave0) + v-projection GEMM (all waves).
__global__ __launch_bounds__(256, 4)
void k_sqskv(const float* __restrict__ x, const float* __restrict__ bv,
             const ushort* __restrict__ uqkb, const ushort* __restrict__ WvT,
             const float* __restrict__ cq, const float* __restrict__ ck,
             ushort* __restrict__ vT, float* __restrict__ sq,
             float* __restrict__ skH){
    __shared__ ushort xb[16][264];   // bf16 x rows
    int t = threadIdx.x;
    int r0 = blockIdx.x * 16;
    int b  = r0 >> 11;
    int j0 = r0 & (NN-1);
    #pragma unroll
    for(int i=0;i<16;i++) xb[i][t] = f2bf(x[((size_t)r0+i)*DD + t]);
    __syncthreads();

    int wv = t>>6, l = t&63, lr = l&15, kg = l>>4;

    // wave 0: scores: C[i][n] = sum_k xb[i][k]*uqkb[n][k]  (M=16 real rows)
    if(wv == 0){
        f32x4 acc = (f32x4){0.f,0.f,0.f,0.f};
        #pragma unroll
        for(int ks=0; ks<8; ks++){
            bf16x8 a = *reinterpret_cast<const bf16x8*>(&xb[lr][ks*32 + kg*8]);
            bf16x8 bb = *reinterpret_cast<const bf16x8*>(uqkb + (size_t)lr*DD + ks*32 + kg*8);
            acc = __builtin_amdgcn_mfma_f32_16x16x32_bf16(a, bb, acc, 0,0,0);
        }
        #pragma unroll
        for(int rg=0; rg<4; rg++){
            int i = kg*4 + rg;
            int R = r0 + i;
            float vsc = acc[rg];
            if(lr < 8) sq[(size_t)R*HH + lr] = vsc + cq[lr];
            else       skH[((size_t)b*NN + (R & (NN-1)))*HH + (lr-8)] = vsc + ck[lr-8];
        }
    }

    // v GEMM: wave wv -> n-tiles 4wv..4wv+3; C[i][n]; store vT[b][n][j0+i]
    f32x4 vacc[4];
    #pragma unroll
    for(int q=0;q<4;q++) vacc[q] = (f32x4){0.f,0.f,0.f,0.f};
    #pragma unroll
    for(int ks=0; ks<8; ks++){
        bf16x8 a = *reinterpret_cast<const bf16x8*>(&xb[lr][ks*32 + kg*8]);
        #pragma unroll
        for(int q=0;q<4;q++){
            int n0 = (wv*4+q)*16;
            bf16x8 bb = *reinterpret_cast<const bf16x8*>(WvT + (size_t)(n0+lr)*DD + ks*32 + kg*8);
            vacc[q] = __builtin_amdgcn_mfma_f32_16x16x32_bf16(a, bb, vacc[q], 0,0,0);
        }
    }
    #pragma unroll
    for(int q=0;q<4;q++){
        int n = (wv*4+q)*16 + lr;
        float bvn = bv[n];
        ushort4 pk;
        pk.x = f2bf(vacc[q][0] + bvn);
        pk.y = f2bf(vacc[q][1] + bvn);
        pk.z = f2bf(vacc[q][2] + bvn);
        pk.w = f2bf(vacc[q][3] + bvn);
        *reinterpret_cast<ushort4*>(&vT[((size_t)b*DD + n)*NN + j0 + kg*4]) = pk;
    }
}

// K1b: Mk[b][h] = max_j skH[b][j][h]
__global__ void k_maxsk(const float* __restrict__ skH, float* __restrict__ Mk){
    int b = blockIdx.x >> 3, h = blockIdx.x & 7;
    int t = threadIdx.x;
    float m = -1e30f;
    for(int j=t; j<NN; j+=256) m = fmaxf(m, skH[((size_t)b*NN + j)*HH + h]);
    #pragma unroll
    for(int off=32; off>=1; off>>=1) m = fmaxf(m, __shfl_xor(m, off));
    __shared__ float red[4];
    if((t&63)==0) red[t>>6] = m;
    __syncthreads();
    if(t==0) Mk[blockIdx.x] = fmaxf(fmaxf(red[0],red[1]), fmaxf(red[2],red[3]));
}

// K2: 2 rows/block, raw adj in, Madj + adj-bitmask out (pack free — adj already read here)
__global__ void k_denom(const int* __restrict__ adj, const float* __restrict__ sq,
                        const float* __restrict__ skH, const float* __restrict__ Mk,
                        float* __restrict__ Madj, unsigned* __restrict__ adjm){
    int r0 = blockIdx.x*2;          // rows r0, r0+1 (same b)
    int b = r0 >> 11;
    int t = threadIdx.x;
    int w = t>>6, l = t&63;
    float sq1[HH], sq2[HH], M1[HH], M2[HH], s1[HH], s2[HH];
    {
        float4 a0 = *reinterpret_cast<const float4*>(&sq[(size_t)r0*HH]);
        float4 a1 = *reinterpret_cast<const float4*>(&sq[(size_t)r0*HH+4]);
        float4 b0 = *reinterpret_cast<const float4*>(&sq[(size_t)(r0+1)*HH]);
        float4 b1 = *reinterpret_cast<const float4*>(&sq[(size_t)(r0+1)*HH+4]);
        float4 m0 = *reinterpret_cast<const float4*>(&Mk[b*HH]);
        float4 m1 = *reinterpret_cast<const float4*>(&Mk[b*HH+4]);
        sq1[0]=a0.x; sq1[1]=a0.y; sq1[2]=a0.z; sq1[3]=a0.w;
        sq1[4]=a1.x; sq1[5]=a1.y; sq1[6]=a1.z; sq1[7]=a1.w;
        sq2[0]=b0.x; sq2[1]=b0.y; sq2[2]=b0.z; sq2[3]=b0.w;
        sq2[4]=b1.x; sq2[5]=b1.y; sq2[6]=b1.z; sq2[7]=b1.w;
        float mk[8] = {m0.x,m0.y,m0.z,m0.w,m1.x,m1.y,m1.z,m1.w};
        #pragma unroll
        for(int h=0;h<HH;h++){
            M1[h] = lky(sq1[h]+mk[h]); M2[h] = lky(sq2[h]+mk[h]);
            s1[h]=0.f; s2[h]=0.f;
        }
    }
    const int* arow1 = adj + (size_t)r0*NN;
    const int* arow2 = adj + ((size_t)r0+1)*NN;
    for(int j0=0; j0<NN; j0+=256){
        int j = j0 + t;
        int a1 = arow1[j];
        int a2 = arow2[j];
        {
            unsigned long long m1b = __ballot(a1 != 0);
            unsigned long long m2b = __ballot(a2 != 0);
            int cw = (j0 >> 5) + w*2;
            if(l == 0){
                adjm[(size_t)r0*64 + cw]       = (unsigned)m1b;
                adjm[((size_t)r0+1)*64 + cw]   = (unsigned)m2b;
            }
            if(l == 32){
                adjm[(size_t)r0*64 + cw + 1]     = (unsigned)(m1b >> 32);
                adjm[((size_t)r0+1)*64 + cw + 1] = (unsigned)(m2b >> 32);
            }
        }
        float4 v0 = *reinterpret_cast<const float4*>(&skH[((size_t)b*NN + j)*HH]);
        float4 v1 = *reinterpret_cast<const float4*>(&skH[((size_t)b*NN + j)*HH+4]);
        float sk[8] = {v0.x,v0.y,v0.z,v0.w,v1.x,v1.y,v1.z,v1.w};
        #pragma unroll
        for(int h=0; h<HH; h++){
            float e1 = exp2raw(lky(sq1[h]+sk[h]) - M1[h]);
            float e2 = exp2raw(lky(sq2[h]+sk[h]) - M2[h]);
            s1[h] += a1 ? e1 : 0.f;
            s2[h] += a2 ? e2 : 0.f;
        }
    }
    #pragma unroll
    for(int h=0;h<HH;h++){
        #pragma unroll
        for(int off=32; off>=1; off>>=1){
            s1[h] += __shfl_xor(s1[h], off);
            s2[h] += __shfl_xor(s2[h], off);
        }
    }
    __shared__ float red[4][16];
    if(l==0){
        #pragma unroll
        for(int h=0;h<HH;h++){ red[w][h]=s1[h]; red[w][8+h]=s2[h]; }
    }
    __syncthreads();
    if(t < 16){
        float s = red[0][t]+red[1][t]+red[2][t]+red[3][t];
        int h = t & 7;
        if(t < 8) Madj[(size_t)r0*HH + h]     = M1[h] + log2f(s);
        else      Madj[((size_t)r0+1)*HH + h] = M2[h] + log2f(s);
    }
}

// K3 (R13/R15/R17 verified variant): adjm bitmask, loads after barrier, XOR-swizzled epilogue.
#define TI 32
#define JT 32
#define JC 8
#define JPC (NN/JC)   // 256

__global__ __launch_bounds__(256, 4)
void k_attn(const unsigned* __restrict__ adjm, const float* __restrict__ sq,
            const float* __restrict__ skH, const float* __restrict__ Madj,
            const ushort* __restrict__ vT, float* __restrict__ meanw,
            ushort* __restrict__ attp){
    __shared__ __align__(16) char smem[40960];
    ushort (*wLDS)[TI][40] = (ushort (*)[TI][40])smem;           // [h][i][j] 20480B
    ushort (*vLDS)[40]     = (ushort (*)[40])(smem + 20480);     // [d][j]    20480B
    float* fb = (float*)smem;                                     // epilogue 32KB

    int t  = threadIdx.x;
    int it = blockIdx.x;
    int b  = blockIdx.y;
    int jc = blockIdx.z;
    int i0 = it*TI;
    int R0 = b*NN + i0;

    int ia = t >> 4;
    int jp = t & 15;
    int jj = jp*2;

    float sq1[8], sq2[8], M1[8], M2[8];
    {
        float4 a0 = *reinterpret_cast<const float4*>(&sq[(size_t)(R0+ia)*HH]);
        float4 a1 = *reinterpret_cast<const float4*>(&sq[(size_t)(R0+ia)*HH+4]);
        float4 b0 = *reinterpret_cast<const float4*>(&sq[(size_t)(R0+16+ia)*HH]);
        float4 b1 = *reinterpret_cast<const float4*>(&sq[(size_t)(R0+16+ia)*HH+4]);
        sq1[0]=a0.x; sq1[1]=a0.y; sq1[2]=a0.z; sq1[3]=a0.w;
        sq1[4]=a1.x; sq1[5]=a1.y; sq1[6]=a1.z; sq1[7]=a1.w;
        sq2[0]=b0.x; sq2[1]=b0.y; sq2[2]=b0.z; sq2[3]=b0.w;
        sq2[4]=b1.x; sq2[5]=b1.y; sq2[6]=b1.z; sq2[7]=b1.w;
        float4 c0 = *reinterpret_cast<const float4*>(&Madj[(size_t)(R0+ia)*HH]);
        float4 c1 = *reinterpret_cast<const float4*>(&Madj[(size_t)(R0+ia)*HH+4]);
        float4 d0 = *reinterpret_cast<const float4*>(&Madj[(size_t)(R0+16+ia)*HH]);
        float4 d1 = *reinterpret_cast<const float4*>(&Madj[(size_t)(R0+16+ia)*HH+4]);
        M1[0]=c0.x; M1[1]=c0.y; M1[2]=c0.z; M1[3]=c0.w;
        M1[4]=c1.x; M1[5]=c1.y; M1[6]=c1.z; M1[7]=c1.w;
        M2[0]=d0.x; M2[1]=d0.y; M2[2]=d0.z; M2[3]=d0.w;
        M2[4]=d1.x; M2[5]=d1.y; M2[6]=d1.z; M2[7]=d1.w;
    }

    int wid = t >> 6;
    int l   = t & 63;
    int lr  = l & 15;
    int kg  = l >> 4;

    f32x4 acc[2][2][2];
    #pragma unroll
    for(int hh=0;hh<2;hh++)
        #pragma unroll
        for(int mi=0;mi<2;mi++)
            #pragma unroll
            for(int ni=0;ni<2;ni++) acc[hh][mi][ni] = (f32x4){0.f,0.f,0.f,0.f};

    const ushort* vsrc = vT + ((size_t)b*DD + t)*NN;
    const float* skbase = skH + (size_t)b*NN*HH;
    const unsigned* mArow = adjm + (size_t)(R0+ia)*64 + jc*8;
    const unsigned* mBrow = adjm + (size_t)(R0+16+ia)*64 + jc*8;

    for(int jt=0; jt<JPC/JT; jt++){
        int jb = jc*JPC + jt*JT;

        __syncthreads();   // prev tile MFMA done reading wLDS/vLDS

        // stage v to LDS (loads AFTER barrier — proven placement)
        {
            const ushort* src = vsrc + jb;
            u16x8 v0 = *reinterpret_cast<const u16x8*>(src);
            u16x8 v1 = *reinterpret_cast<const u16x8*>(src+8);
            u16x8 v2 = *reinterpret_cast<const u16x8*>(src+16);
            u16x8 v3 = *reinterpret_cast<const u16x8*>(src+24);
            *reinterpret_cast<u16x8*>(&vLDS[t][0])  = v0;
            *reinterpret_cast<u16x8*>(&vLDS[t][8])  = v1;
            *reinterpret_cast<u16x8*>(&vLDS[t][16]) = v2;
            *reinterpret_cast<u16x8*>(&vLDS[t][24]) = v3;
        }

        // Phase A
        {
            float4 p0 = *reinterpret_cast<const float4*>(&skbase[(size_t)(jb+jj)*HH]);
            float4 p1 = *reinterpret_cast<const float4*>(&skbase[(size_t)(jb+jj)*HH+4]);
            float4 q0 = *reinterpret_cast<const float4*>(&skbase[(size_t)(jb+jj+1)*HH]);
            float4 q1 = *reinterpret_cast<const float4*>(&skbase[(size_t)(jb+jj+1)*HH+4]);
            unsigned wA = mArow[jt];
            unsigned wB = mBrow[jt];
            float ska[8] = {p0.x,p0.y,p0.z,p0.w,p1.x,p1.y,p1.z,p1.w};
            float skb[8] = {q0.x,q0.y,q0.z,q0.w,q1.x,q1.y,q1.z,q1.w};
            unsigned bA = (wA >> jj) & 3u;
            unsigned bB = (wB >> jj) & 3u;
            f32x2 wsA = {0.f,0.f}, wsB = {0.f,0.f};
            #pragma unroll
            for(int h=0; h<HH; h++){
                float eA0 = exp2raw(lky(sq1[h]+ska[h]) - M1[h]);
                float eA1 = exp2raw(lky(sq1[h]+skb[h]) - M1[h]);
                float eB0 = exp2raw(lky(sq2[h]+ska[h]) - M2[h]);
                float eB1 = exp2raw(lky(sq2[h]+skb[h]) - M2[h]);
                float w00 = (bA&1u) ? eA0 : 0.f;
                float w01 = (bA&2u) ? eA1 : 0.f;
                float w10 = (bB&1u) ? eB0 : 0.f;
                float w11 = (bB&2u) ? eB1 : 0.f;
                wsA += (f32x2){w00, w01};
                wsB += (f32x2){w10, w11};
                *reinterpret_cast<unsigned*>(&wLDS[h][ia][jj])    = cvtpk(w00, w01);
                *reinterpret_cast<unsigned*>(&wLDS[h][16+ia][jj]) = cvtpk(w10, w11);
            }
            wsA *= 0.125f; wsB *= 0.125f;
            *reinterpret_cast<f32x2*>(&meanw[((size_t)(R0+ia))*NN + jb + jj])    = wsA;
            *reinterpret_cast<f32x2*>(&meanw[((size_t)(R0+16+ia))*NN + jb + jj]) = wsB;
        }
        __syncthreads();

        // Phase B: MFMA
        #pragma unroll
        for(int hh=0; hh<2; hh++){
            int h = wid*2 + hh;
            bf16x8 a0 = *reinterpret_cast<const bf16x8*>(&wLDS[h][lr][kg*8]);
            bf16x8 a1 = *reinterpret_cast<const bf16x8*>(&wLDS[h][16+lr][kg*8]);
            bf16x8 b0 = *reinterpret_cast<const bf16x8*>(&vLDS[h*HD + lr][kg*8]);
            bf16x8 b1 = *reinterpret_cast<const bf16x8*>(&vLDS[h*HD + 16 + lr][kg*8]);
            acc[hh][0][0] = __builtin_amdgcn_mfma_f32_16x16x32_bf16(a0, b0, acc[hh][0][0], 0,0,0);
            acc[hh][0][1] = __builtin_amdgcn_mfma_f32_16x16x32_bf16(a0, b1, acc[hh][0][1], 0,0,0);
            acc[hh][1][0] = __builtin_amdgcn_mfma_f32_16x16x32_bf16(a1, b0, acc[hh][1][0], 0,0,0);
            acc[hh][1][1] = __builtin_amdgcn_mfma_f32_16x16x32_bf16(a1, b1, acc[hh][1][1], 0,0,0);
        }
    }

    // Epilogue: XOR-swizzled fb, coalesced bf16 stores
    __syncthreads();
    #pragma unroll
    for(int hh=0;hh<2;hh++)
        #pragma unroll
        for(int mi=0;mi<2;mi++)
            #pragma unroll
            for(int ni=0;ni<2;ni++)
                #pragma unroll
                for(int rg=0; rg<4; rg++){
                    int i = mi*16 + kg*4 + rg;
                    int d = (wid*2+hh)*HD + ni*16 + lr;
                    fb[i*256 + (d ^ ((i&7)<<2))] = acc[hh][mi][ni][rg];
                }
    __syncthreads();
    {
        int i  = t >> 3;              // 0..31 row; 8 threads per row
        int d0 = (t & 7) * 32;        // contiguous 512B per row across 8 threads
        int swz = (i & 7) << 2;
        size_t orow = ((size_t)(jc*BB + b)*NN + i0 + i)*DD + d0;
        #pragma unroll
        for(int qq=0; qq<4; qq++){
            float4 f0 = *reinterpret_cast<const float4*>(&fb[i*256 + ((d0 + qq*8)     ^ swz)]);
            float4 f1 = *reinterpret_cast<const float4*>(&fb[i*256 + ((d0 + qq*8 + 4) ^ swz)]);
            uint4 pk;
            pk.x = cvtpk(f0.x, f0.y); pk.y = cvtpk(f0.z, f0.w);
            pk.z = cvtpk(f1.x, f1.y); pk.w = cvtpk(f1.z, f1.w);
            *reinterpret_cast<uint4*>(&attp[orow + qq*8]) = pk;
        }
    }
}

// K4: out = LN( (sum attp) @ Wo + bo + x ) — MFMA GEMM, 16 real rows/block.
__global__ __launch_bounds__(256, 2)
void k_out(const ushort* __restrict__ attp, const float* __restrict__ x,
           const ushort* __restrict__ WoT, const float* __restrict__ bo,
           const float* __restrict__ g, const float* __restrict__ bln,
           float* __restrict__ out){
    __shared__ ushort ab[16][264];   // bf16 attended, 16 real rows
    __shared__ float fbo[16][260];   // GEMM result / LN scratch
    __shared__ float ps[16][16][2];
    __shared__ float muL[16], rsL[16];
    int t = threadIdx.x;
    int r0 = blockIdx.x*16;
    int b  = r0 >> 11;
    int j0 = r0 & (NN-1);

    // sum partials -> ab bf16 (two row-groups of 8)
    #pragma unroll
    for(int rp=0; rp<2; rp++){
        int rr = rp*8 + (t >> 5);
        int d0 = (t & 31) * 8;
        float s8[8];
        #pragma unroll
        for(int e=0;e<8;e++) s8[e]=0.f;
        #pragma unroll
        for(int jc=0; jc<JC; jc++){
            u16x8 v = *reinterpret_cast<const u16x8*>(&attp[((size_t)(jc*BB + b)*NN + j0 + rr)*DD + d0]);
            #pragma unroll
            for(int e=0;e<8;e++) s8[e] += bf2f(v[e]);
        }
        u16x8 pack;
        #pragma unroll
        for(int e=0;e<8;e++) pack[e] = f2bf(s8[e]);
        *reinterpret_cast<u16x8*>(&ab[rr][d0]) = pack;
    }
    __syncthreads();

    // MFMA GEMM: wave wv handles n-tiles 4wv..4wv+3, M=16 all-real
    {
        int wv = t>>6, l = t&63, lr = l&15, kg = l>>4;
        f32x4 acc0 = (f32x4){0.f,0.f,0.f,0.f};
        f32x4 acc1 = (f32x4){0.f,0.f,0.f,0.f};
        f32x4 acc2 = (f32x4){0.f,0.f,0.f,0.f};
        f32x4 acc3 = (f32x4){0.f,0.f,0.f,0.f};
        #pragma unroll
        for(int ks=0; ks<8; ks++){
            bf16x8 a = *reinterpret_cast<const bf16x8*>(&ab[lr][ks*32 + kg*8]);
            bf16x8 b0 = *reinterpret_cast<const bf16x8*>(WoT + (size_t)((wv*4+0)*16 + lr)*DD + ks*32 + kg*8);
            bf16x8 b1 = *reinterpret_cast<const bf16x8*>(WoT + (size_t)((wv*4+1)*16 + lr)*DD + ks*32 + kg*8);
            bf16x8 b2 = *reinterpret_cast<const bf16x8*>(WoT + (size_t)((wv*4+2)*16 + lr)*DD + ks*32 + kg*8);
            bf16x8 b3 = *reinterpret_cast<const bf16x8*>(WoT + (size_t)((wv*4+3)*16 + lr)*DD + ks*32 + kg*8);
            acc0 = __builtin_amdgcn_mfma_f32_16x16x32_bf16(a, b0, acc0, 0,0,0);
            acc1 = __builtin_amdgcn_mfma_f32_16x16x32_bf16(a, b1, acc1, 0,0,0);
            acc2 = __builtin_amdgcn_mfma_f32_16x16x32_bf16(a, b2, acc2, 0,0,0);
            acc3 = __builtin_amdgcn_mfma_f32_16x16x32_bf16(a, b3, acc3, 0,0,0);
        }
        #pragma unroll
        for(int rg=0; rg<4; rg++){
            int i = kg*4 + rg;
            fbo[i][(wv*4+0)*16 + lr] = acc0[rg];
            fbo[i][(wv*4+1)*16 + lr] = acc1[rg];
            fbo[i][(wv*4+2)*16 + lr] = acc2[rg];
            fbo[i][(wv*4+3)*16 + lr] = acc3[rg];
        }
    }
    __syncthreads();

    // residual + LN (thread t = col)
    float accr[16];
    float bb = bo[t];
    #pragma unroll
    for(int r=0;r<16;r++) accr[r] = fbo[r][t] + bb + x[((size_t)r0+r)*DD + t];
    __syncthreads();
    #pragma unroll
    for(int r=0;r<16;r++) fbo[r][t] = accr[r];
    __syncthreads();
    {
        int rr = t>>4, seg = t&15;
        float s=0.f, sqs=0.f;
        #pragma unroll
        for(int e=0;e<16;e++){
            float y = fbo[rr][seg*16+e];
            s += y; sqs += y*y;
        }
        ps[rr][seg][0]=s; ps[rr][seg][1]=sqs;
    }
    __syncthreads();
    if(t<16){
        float s=0.f, sqs=0.f;
        #pragma unroll
        for(int e=0;e<16;e++){ s+=ps[t][e][0]; sqs+=ps[t][e][1]; }
        float mu = s/256.f;
        float var = sqs/256.f - mu*mu;
        muL[t]=mu; rsL[t]=rsqrtf(var+EPS);
    }
    __syncthreads();
    float gg = g[t], bl = bln[t];
    #pragma unroll
    for(int r=0;r<16;r++){
        out[((size_t)r0+r)*DD + t] = (accr[r]-muL[r])*rsL[r]*gg + bl;
    }
}

extern "C" void kernel_launch(void* const* d_in, const int* in_sizes, int n_in,
                              void* d_out, int out_size, void* d_ws, size_t ws_size,
                              hipStream_t stream) {
    const float* x    = (const float*)d_in[0];
    const int*   adj  = (const int*)d_in[1];
    const float* Wq   = (const float*)d_in[2];
    const float* bq   = (const float*)d_in[3];
    const float* Wk   = (const float*)d_in[4];
    const float* bk   = (const float*)d_in[5];
    const float* Wv   = (const float*)d_in[6];
    const float* bv   = (const float*)d_in[7];
    const float* aa   = (const float*)d_in[8];
    const float* Wo   = (const float*)d_in[9];
    const float* bo   = (const float*)d_in[10];
    const float* lng  = (const float*)d_in[11];
    const float* lnb  = (const float*)d_in[12];

    float* out0  = (float*)d_out;                  // (B,N,D)
    float* meanw = out0 + (size_t)BB*NN*DD;        // (B,N,N)

    char* wsb = (char*)d_ws;
    float* cq   = (float*)wsb;                                    // 16
    float* ck   = cq + 16;                                        // 16
    float* Mk   = ck + 16;                                        // 16 (+pad)
    float* sqv  = Mk + 80;                                        // 32768
    float* skH  = sqv + 32768;                                    // 32768
    float* Madj = skH + 32768;                                    // 32768
    unsigned* adjm = (unsigned*)(Madj + 32768);                   // BB*NN*64 u32 = 1MB
    ushort* uqkb= (ushort*)(adjm + (size_t)BB*NN*64);             // 16*256 u16
    ushort* WoT = uqkb + 16*DD;                                   // 256*256 u16
    ushort* WvT = WoT + (size_t)DD*DD;                            // 256*256 u16
    ushort* vT  = WvT + (size_t)DD*DD;                            // BB*DD*NN u16
    ushort* attp= vT + (size_t)BB*DD*NN;                          // JC*BB*NN*DD u16

    k_prep<<<136, 256, 0, stream>>>(Wq, bq, Wk, bk, aa, Wo, Wv, uqkb, cq, ck, WoT, WvT);
    k_sqskv<<<(BB*NN)/16, 256, 0, stream>>>(x, bv, uqkb, WvT, cq, ck, vT, sqv, skH);
    k_maxsk<<<BB*HH, 256, 0, stream>>>(skH, Mk);
    k_denom<<<(BB*NN)/2, 256, 0, stream>>>(adj, sqv, skH, Mk, Madj, adjm);
    k_attn<<<dim3(NN/TI, BB, JC), 256, 0, stream>>>(adjm, sqv, skH, Madj, vT, meanw, attp);
    k_out<<<(BB*NN)/16, 256, 0, stream>>>(attp, x, WoT, bo, lng, lnb, out0);
}

// Round 20
// 88.954 us; speedup vs baseline: 3.1393x; 1.0265x over previous
//
#include <hip/hip_runtime.h>

#define BB 2
#define NN 2048
#define DD 256
#define HH 8
#define HD 32
#define EPS 1e-5f
#define L2E 1.4426950408889634f

typedef __attribute__((ext_vector_type(8))) short bf16x8;
typedef __attribute__((ext_vector_type(4))) float f32x4;
typedef __attribute__((ext_vector_type(2))) float f32x2;
typedef __attribute__((ext_vector_type(8))) unsigned short u16x8;

__device__ __forceinline__ float lky(float z){ return fmaxf(z, 0.2f*z); }

// Raw hardware exp2: valid here because args <= ~0 and args < -126 must yield
// w ~= 0 (flush-to-zero is the correct answer). Avoids OCML's ~5-inst guard.
__device__ __forceinline__ float exp2raw(float x){
    float r;
    asm("v_exp_f32 %0, %1" : "=v"(r) : "v"(x));
    return r;
}

__device__ __forceinline__ ushort f2bf(float f){
    union{ float f; unsigned u; } c; c.f = f;
    unsigned r = c.u + 0x7fffu + ((c.u >> 16) & 1u);
    return (ushort)(r >> 16);
}
__device__ __forceinline__ float bf2f(ushort u){
    union{ unsigned u; float f; } c; c.u = ((unsigned)u) << 16; return c.f;
}
__device__ __forceinline__ unsigned cvtpk(float lo, float hi){
    unsigned r;
    asm("v_cvt_pk_bf16_f32 %0, %1, %2" : "=v"(r) : "v"(lo), "v"(hi));
    return r;
}

// K0: blocks 0-7: uqkb bf16 + cq/ck (log2e-scaled); 8-71: WoT; 72-135: WvT.
__global__ void k_prep(const float* __restrict__ Wq, const float* __restrict__ bq,
                       const float* __restrict__ Wk, const float* __restrict__ bk,
                       const float* __restrict__ aa, const float* __restrict__ Wo,
                       const float* __restrict__ Wv,
                       ushort* __restrict__ uqkb, float* __restrict__ cq,
                       float* __restrict__ ck, ushort* __restrict__ WoT,
                       ushort* __restrict__ WvT){
    int t = threadIdx.x;
    if(blockIdx.x < 8){
        int h = blockIdx.x;
        int d = t;
        float accq = 0.f, acck = 0.f;
        #pragma unroll
        for(int k=0; k<HD; k++){
            accq += Wq[(size_t)d*DD + h*HD + k] * aa[h*2*HD + k];
            acck += Wk[(size_t)d*DD + h*HD + k] * aa[h*2*HD + HD + k];
        }
        uqkb[h*DD + d]     = f2bf(accq * L2E);
        uqkb[(8+h)*DD + d] = f2bf(acck * L2E);
        __shared__ float red[64];
        if(d < HD){
            red[d]      = bq[h*HD+d]*aa[h*2*HD+d];
            red[32+d]   = bk[h*HD+d]*aa[h*2*HD+HD+d];
        }
        __syncthreads();
        if(d==0){ float s=0.f; for(int k=0;k<32;k++) s+=red[k];    cq[h]=s*L2E; }
        if(d==1){ float s=0.f; for(int k=0;k<32;k++) s+=red[32+k]; ck[h]=s*L2E; }
    } else if(blockIdx.x < 72){
        int blk = blockIdx.x - 8;     // 0..63
        int wv = t>>6, l = t&63;
        int tile = blk*4 + wv;        // 0..255
        int tr = (tile>>4)*16, tc = (tile&15)*16;
        #pragma unroll
        for(int e=0;e<4;e++){
            int idx = l*4+e;
            int kk = tr + (idx>>4);
            int nn = tc + (idx&15);
            WoT[(size_t)nn*DD + kk] = f2bf(Wo[(size_t)kk*DD + nn]);
        }
    } else {
        int blk = blockIdx.x - 72;    // 0..63
        int wv = t>>6, l = t&63;
        int tile = blk*4 + wv;
        int tr = (tile>>4)*16, tc = (tile&15)*16;
        #pragma unroll
        for(int e=0;e<4;e++){
            int idx = l*4+e;
            int kk = tr + (idx>>4);
            int nn = tc + (idx&15);
            WvT[(size_t)nn*DD + kk] = f2bf(Wv[(size_t)kk*DD + nn]);
        }
    }
}

// K1: 16 rows/block, full MFMA: scores (wave0) + v-projection GEMM (all waves).
__global__ __launch_bounds__(256, 4)
void k_sqskv(const float* __restrict__ x, const float* __restrict__ bv,
             const ushort* __restrict__ uqkb, const ushort* __restrict__ WvT,
             const float* __restrict__ cq, const float* __restrict__ ck,
             ushort* __restrict__ vT, float* __restrict__ sq,
             float* __restrict__ skH){
    __shared__ ushort xb[16][264];   // bf16 x rows
    int t = threadIdx.x;
    int r0 = blockIdx.x * 16;
    int b  = r0 >> 11;
    int j0 = r0 & (NN-1);
    #pragma unroll
    for(int i=0;i<16;i++) xb[i][t] = f2bf(x[((size_t)r0+i)*DD + t]);
    __syncthreads();

    int wv = t>>6, l = t&63, lr = l&15, kg = l>>4;

    // wave 0: scores: C[i][n] = sum_k xb[i][k]*uqkb[n][k]  (M=16 real rows)
    if(wv == 0){
        f32x4 acc = (f32x4){0.f,0.f,0.f,0.f};
        #pragma unroll
        for(int ks=0; ks<8; ks++){
            bf16x8 a = *reinterpret_cast<const bf16x8*>(&xb[lr][ks*32 + kg*8]);
            bf16x8 bb = *reinterpret_cast<const bf16x8*>(uqkb + (size_t)lr*DD + ks*32 + kg*8);
            acc = __builtin_amdgcn_mfma_f32_16x16x32_bf16(a, bb, acc, 0,0,0);
        }
        #pragma unroll
        for(int rg=0; rg<4; rg++){
            int i = kg*4 + rg;
            int R = r0 + i;
            float vsc = acc[rg];
            if(lr < 8) sq[(size_t)R*HH + lr] = vsc + cq[lr];
            else       skH[((size_t)b*NN + (R & (NN-1)))*HH + (lr-8)] = vsc + ck[lr-8];
        }
    }

    // v GEMM: wave wv -> n-tiles 4wv..4wv+3; C[i][n]; store vT[b][n][j0+i]
    f32x4 vacc[4];
    #pragma unroll
    for(int q=0;q<4;q++) vacc[q] = (f32x4){0.f,0.f,0.f,0.f};
    #pragma unroll
    for(int ks=0; ks<8; ks++){
        bf16x8 a = *reinterpret_cast<const bf16x8*>(&xb[lr][ks*32 + kg*8]);
        #pragma unroll
        for(int q=0;q<4;q++){
            int n0 = (wv*4+q)*16;
            bf16x8 bb = *reinterpret_cast<const bf16x8*>(WvT + (size_t)(n0+lr)*DD + ks*32 + kg*8);
            vacc[q] = __builtin_amdgcn_mfma_f32_16x16x32_bf16(a, bb, vacc[q], 0,0,0);
        }
    }
    #pragma unroll
    for(int q=0;q<4;q++){
        int n = (wv*4+q)*16 + lr;
        float bvn = bv[n];
        ushort4 pk;
        pk.x = f2bf(vacc[q][0] + bvn);
        pk.y = f2bf(vacc[q][1] + bvn);
        pk.z = f2bf(vacc[q][2] + bvn);
        pk.w = f2bf(vacc[q][3] + bvn);
        *reinterpret_cast<ushort4*>(&vT[((size_t)b*DD + n)*NN + j0 + kg*4]) = pk;
    }
}

// K1b: Mk[b][h] = max_j skH[b][j][h]
__global__ void k_maxsk(const float* __restrict__ skH, float* __restrict__ Mk){
    int b = blockIdx.x >> 3, h = blockIdx.x & 7;
    int t = threadIdx.x;
    float m = -1e30f;
    for(int j=t; j<NN; j+=256) m = fmaxf(m, skH[((size_t)b*NN + j)*HH + h]);
    #pragma unroll
    for(int off=32; off>=1; off>>=1) m = fmaxf(m, __shfl_xor(m, off));
    __shared__ float red[4];
    if((t&63)==0) red[t>>6] = m;
    __syncthreads();
    if(t==0) Mk[blockIdx.x] = fmaxf(fmaxf(red[0],red[1]), fmaxf(red[2],red[3]));
}

// K2: 2 rows/block, raw adj in, Madj + adj-bitmask out (pack free — adj already read here)
__global__ void k_denom(const int* __restrict__ adj, const float* __restrict__ sq,
                        const float* __restrict__ skH, const float* __restrict__ Mk,
                        float* __restrict__ Madj, unsigned* __restrict__ adjm){
    int r0 = blockIdx.x*2;          // rows r0, r0+1 (same b)
    int b = r0 >> 11;
    int t = threadIdx.x;
    int w = t>>6, l = t&63;
    float sq1[HH], sq2[HH], M1[HH], M2[HH], s1[HH], s2[HH];
    {
        float4 a0 = *reinterpret_cast<const float4*>(&sq[(size_t)r0*HH]);
        float4 a1 = *reinterpret_cast<const float4*>(&sq[(size_t)r0*HH+4]);
        float4 b0 = *reinterpret_cast<const float4*>(&sq[(size_t)(r0+1)*HH]);
        float4 b1 = *reinterpret_cast<const float4*>(&sq[(size_t)(r0+1)*HH+4]);
        float4 m0 = *reinterpret_cast<const float4*>(&Mk[b*HH]);
        float4 m1 = *reinterpret_cast<const float4*>(&Mk[b*HH+4]);
        sq1[0]=a0.x; sq1[1]=a0.y; sq1[2]=a0.z; sq1[3]=a0.w;
        sq1[4]=a1.x; sq1[5]=a1.y; sq1[6]=a1.z; sq1[7]=a1.w;
        sq2[0]=b0.x; sq2[1]=b0.y; sq2[2]=b0.z; sq2[3]=b0.w;
        sq2[4]=b1.x; sq2[5]=b1.y; sq2[6]=b1.z; sq2[7]=b1.w;
        float mk[8] = {m0.x,m0.y,m0.z,m0.w,m1.x,m1.y,m1.z,m1.w};
        #pragma unroll
        for(int h=0;h<HH;h++){
            M1[h] = lky(sq1[h]+mk[h]); M2[h] = lky(sq2[h]+mk[h]);
            s1[h]=0.f; s2[h]=0.f;
        }
    }
    const int* arow1 = adj + (size_t)r0*NN;
    const int* arow2 = adj + ((size_t)r0+1)*NN;
    for(int j0=0; j0<NN; j0+=256){
        int j = j0 + t;
        int a1 = arow1[j];
        int a2 = arow2[j];
        {
            unsigned long long m1b = __ballot(a1 != 0);
            unsigned long long m2b = __ballot(a2 != 0);
            int cw = (j0 >> 5) + w*2;
            if(l == 0){
                adjm[(size_t)r0*64 + cw]       = (unsigned)m1b;
                adjm[((size_t)r0+1)*64 + cw]   = (unsigned)m2b;
            }
            if(l == 32){
                adjm[(size_t)r0*64 + cw + 1]     = (unsigned)(m1b >> 32);
                adjm[((size_t)r0+1)*64 + cw + 1] = (unsigned)(m2b >> 32);
            }
        }
        float4 v0 = *reinterpret_cast<const float4*>(&skH[((size_t)b*NN + j)*HH]);
        float4 v1 = *reinterpret_cast<const float4*>(&skH[((size_t)b*NN + j)*HH+4]);
        float sk[8] = {v0.x,v0.y,v0.z,v0.w,v1.x,v1.y,v1.z,v1.w};
        #pragma unroll
        for(int h=0; h<HH; h++){
            float e1 = exp2raw(lky(sq1[h]+sk[h]) - M1[h]);
            float e2 = exp2raw(lky(sq2[h]+sk[h]) - M2[h]);
            s1[h] += a1 ? e1 : 0.f;
            s2[h] += a2 ? e2 : 0.f;
        }
    }
    #pragma unroll
    for(int h=0;h<HH;h++){
        #pragma unroll
        for(int off=32; off>=1; off>>=1){
            s1[h] += __shfl_xor(s1[h], off);
            s2[h] += __shfl_xor(s2[h], off);
        }
    }
    __shared__ float red[4][16];
    if(l==0){
        #pragma unroll
        for(int h=0;h<HH;h++){ red[w][h]=s1[h]; red[w][8+h]=s2[h]; }
    }
    __syncthreads();
    if(t < 16){
        float s = red[0][t]+red[1][t]+red[2][t]+red[3][t];
        int h = t & 7;
        if(t < 8) Madj[(size_t)r0*HH + h]     = M1[h] + log2f(s);
        else      Madj[((size_t)r0+1)*HH + h] = M2[h] + log2f(s);
    }
}

// K3: same verified structure; JC=4 (fewer attp partials, 16 tiles/block).
#define TI 32
#define JT 32
#define JC 4
#define JPC (NN/JC)   // 512

__global__ __launch_bounds__(256, 4)
void k_attn(const unsigned* __restrict__ adjm, const float* __restrict__ sq,
            const float* __restrict__ skH, const float* __restrict__ Madj,
            const ushort* __restrict__ vT, float* __restrict__ meanw,
            ushort* __restrict__ attp){
    __shared__ __align__(16) char smem[40960];
    ushort (*wLDS)[TI][40] = (ushort (*)[TI][40])smem;           // [h][i][j] 20480B
    ushort (*vLDS)[40]     = (ushort (*)[40])(smem + 20480);     // [d][j]    20480B
    float* fb = (float*)smem;                                     // epilogue 32KB

    int t  = threadIdx.x;
    int it = blockIdx.x;
    int b  = blockIdx.y;
    int jc = blockIdx.z;
    int i0 = it*TI;
    int R0 = b*NN + i0;

    int ia = t >> 4;
    int jp = t & 15;
    int jj = jp*2;

    float sq1[8], sq2[8], M1[8], M2[8];
    {
        float4 a0 = *reinterpret_cast<const float4*>(&sq[(size_t)(R0+ia)*HH]);
        float4 a1 = *reinterpret_cast<const float4*>(&sq[(size_t)(R0+ia)*HH+4]);
        float4 b0 = *reinterpret_cast<const float4*>(&sq[(size_t)(R0+16+ia)*HH]);
        float4 b1 = *reinterpret_cast<const float4*>(&sq[(size_t)(R0+16+ia)*HH+4]);
        sq1[0]=a0.x; sq1[1]=a0.y; sq1[2]=a0.z; sq1[3]=a0.w;
        sq1[4]=a1.x; sq1[5]=a1.y; sq1[6]=a1.z; sq1[7]=a1.w;
        sq2[0]=b0.x; sq2[1]=b0.y; sq2[2]=b0.z; sq2[3]=b0.w;
        sq2[4]=b1.x; sq2[5]=b1.y; sq2[6]=b1.z; sq2[7]=b1.w;
        float4 c0 = *reinterpret_cast<const float4*>(&Madj[(size_t)(R0+ia)*HH]);
        float4 c1 = *reinterpret_cast<const float4*>(&Madj[(size_t)(R0+ia)*HH+4]);
        float4 d0 = *reinterpret_cast<const float4*>(&Madj[(size_t)(R0+16+ia)*HH]);
        float4 d1 = *reinterpret_cast<const float4*>(&Madj[(size_t)(R0+16+ia)*HH+4]);
        M1[0]=c0.x; M1[1]=c0.y; M1[2]=c0.z; M1[3]=c0.w;
        M1[4]=c1.x; M1[5]=c1.y; M1[6]=c1.z; M1[7]=c1.w;
        M2[0]=d0.x; M2[1]=d0.y; M2[2]=d0.z; M2[3]=d0.w;
        M2[4]=d1.x; M2[5]=d1.y; M2[6]=d1.z; M2[7]=d1.w;
    }

    int wid = t >> 6;
    int l   = t & 63;
    int lr  = l & 15;
    int kg  = l >> 4;

    f32x4 acc[2][2][2];
    #pragma unroll
    for(int hh=0;hh<2;hh++)
        #pragma unroll
        for(int mi=0;mi<2;mi++)
            #pragma unroll
            for(int ni=0;ni<2;ni++) acc[hh][mi][ni] = (f32x4){0.f,0.f,0.f,0.f};

    const ushort* vsrc = vT + ((size_t)b*DD + t)*NN;
    const float* skbase = skH + (size_t)b*NN*HH;
    const unsigned* mArow = adjm + (size_t)(R0+ia)*64 + jc*16;
    const unsigned* mBrow = adjm + (size_t)(R0+16+ia)*64 + jc*16;

    for(int jt=0; jt<JPC/JT; jt++){
        int jb = jc*JPC + jt*JT;

        __syncthreads();   // prev tile MFMA done reading wLDS/vLDS

        // stage v to LDS (loads AFTER barrier — proven placement)
        {
            const ushort* src = vsrc + jb;
            u16x8 v0 = *reinterpret_cast<const u16x8*>(src);
            u16x8 v1 = *reinterpret_cast<const u16x8*>(src+8);
            u16x8 v2 = *reinterpret_cast<const u16x8*>(src+16);
            u16x8 v3 = *reinterpret_cast<const u16x8*>(src+24);
            *reinterpret_cast<u16x8*>(&vLDS[t][0])  = v0;
            *reinterpret_cast<u16x8*>(&vLDS[t][8])  = v1;
            *reinterpret_cast<u16x8*>(&vLDS[t][16]) = v2;
            *reinterpret_cast<u16x8*>(&vLDS[t][24]) = v3;
        }

        // Phase A
        {
            float4 p0 = *reinterpret_cast<const float4*>(&skbase[(size_t)(jb+jj)*HH]);
            float4 p1 = *reinterpret_cast<const float4*>(&skbase[(size_t)(jb+jj)*HH+4]);
            float4 q0 = *reinterpret_cast<const float4*>(&skbase[(size_t)(jb+jj+1)*HH]);
            float4 q1 = *reinterpret_cast<const float4*>(&skbase[(size_t)(jb+jj+1)*HH+4]);
            unsigned wA = mArow[jt];
            unsigned wB = mBrow[jt];
            float ska[8] = {p0.x,p0.y,p0.z,p0.w,p1.x,p1.y,p1.z,p1.w};
            float skb[8] = {q0.x,q0.y,q0.z,q0.w,q1.x,q1.y,q1.z,q1.w};
            unsigned bA = (wA >> jj) & 3u;
            unsigned bB = (wB >> jj) & 3u;
            f32x2 wsA = {0.f,0.f}, wsB = {0.f,0.f};
            #pragma unroll
            for(int h=0; h<HH; h++){
                float eA0 = exp2raw(lky(sq1[h]+ska[h]) - M1[h]);
                float eA1 = exp2raw(lky(sq1[h]+skb[h]) - M1[h]);
                float eB0 = exp2raw(lky(sq2[h]+ska[h]) - M2[h]);
                float eB1 = exp2raw(lky(sq2[h]+skb[h]) - M2[h]);
                float w00 = (bA&1u) ? eA0 : 0.f;
                float w01 = (bA&2u) ? eA1 : 0.f;
                float w10 = (bB&1u) ? eB0 : 0.f;
                float w11 = (bB&2u) ? eB1 : 0.f;
                wsA += (f32x2){w00, w01};
                wsB += (f32x2){w10, w11};
                *reinterpret_cast<unsigned*>(&wLDS[h][ia][jj])    = cvtpk(w00, w01);
                *reinterpret_cast<unsigned*>(&wLDS[h][16+ia][jj]) = cvtpk(w10, w11);
            }
            wsA *= 0.125f; wsB *= 0.125f;
            *reinterpret_cast<f32x2*>(&meanw[((size_t)(R0+ia))*NN + jb + jj])    = wsA;
            *reinterpret_cast<f32x2*>(&meanw[((size_t)(R0+16+ia))*NN + jb + jj]) = wsB;
        }
        __syncthreads();

        // Phase B: MFMA
        #pragma unroll
        for(int hh=0; hh<2; hh++){
            int h = wid*2 + hh;
            bf16x8 a0 = *reinterpret_cast<const bf16x8*>(&wLDS[h][lr][kg*8]);
            bf16x8 a1 = *reinterpret_cast<const bf16x8*>(&wLDS[h][16+lr][kg*8]);
            bf16x8 b0 = *reinterpret_cast<const bf16x8*>(&vLDS[h*HD + lr][kg*8]);
            bf16x8 b1 = *reinterpret_cast<const bf16x8*>(&vLDS[h*HD + 16 + lr][kg*8]);
            acc[hh][0][0] = __builtin_amdgcn_mfma_f32_16x16x32_bf16(a0, b0, acc[hh][0][0], 0,0,0);
            acc[hh][0][1] = __builtin_amdgcn_mfma_f32_16x16x32_bf16(a0, b1, acc[hh][0][1], 0,0,0);
            acc[hh][1][0] = __builtin_amdgcn_mfma_f32_16x16x32_bf16(a1, b0, acc[hh][1][0], 0,0,0);
            acc[hh][1][1] = __builtin_amdgcn_mfma_f32_16x16x32_bf16(a1, b1, acc[hh][1][1], 0,0,0);
        }
    }

    // Epilogue: XOR-swizzled fb, coalesced bf16 stores
    __syncthreads();
    #pragma unroll
    for(int hh=0;hh<2;hh++)
        #pragma unroll
        for(int mi=0;mi<2;mi++)
            #pragma unroll
            for(int ni=0;ni<2;ni++)
                #pragma unroll
                for(int rg=0; rg<4; rg++){
                    int i = mi*16 + kg*4 + rg;
                    int d = (wid*2+hh)*HD + ni*16 + lr;
                    fb[i*256 + (d ^ ((i&7)<<2))] = acc[hh][mi][ni][rg];
                }
    __syncthreads();
    {
        int i  = t >> 3;              // 0..31 row; 8 threads per row
        int d0 = (t & 7) * 32;        // contiguous 512B per row across 8 threads
        int swz = (i & 7) << 2;
        size_t orow = ((size_t)(jc*BB + b)*NN + i0 + i)*DD + d0;
        #pragma unroll
        for(int qq=0; qq<4; qq++){
            float4 f0 = *reinterpret_cast<const float4*>(&fb[i*256 + ((d0 + qq*8)     ^ swz)]);
            float4 f1 = *reinterpret_cast<const float4*>(&fb[i*256 + ((d0 + qq*8 + 4) ^ swz)]);
            uint4 pk;
            pk.x = cvtpk(f0.x, f0.y); pk.y = cvtpk(f0.z, f0.w);
            pk.z = cvtpk(f1.x, f1.y); pk.w = cvtpk(f1.z, f1.w);
            *reinterpret_cast<uint4*>(&attp[orow + qq*8]) = pk;
        }
    }
}

// K4: out = LN( (sum attp) @ Wo + bo + x ) — MFMA GEMM, 16 real rows/block.
__global__ __launch_bounds__(256, 2)
void k_out(const ushort* __restrict__ attp, const float* __restrict__ x,
           const ushort* __restrict__ WoT, const float* __restrict__ bo,
           const float* __restrict__ g, const float* __restrict__ bln,
           float* __restrict__ out){
    __shared__ ushort ab[16][264];   // bf16 attended, 16 real rows
    __shared__ float fbo[16][260];   // GEMM result / LN scratch
    __shared__ float ps[16][16][2];
    __shared__ float muL[16], rsL[16];
    int t = threadIdx.x;
    int r0 = blockIdx.x*16;
    int b  = r0 >> 11;
    int j0 = r0 & (NN-1);

    // sum partials -> ab bf16 (two row-groups of 8)
    #pragma unroll
    for(int rp=0; rp<2; rp++){
        int rr = rp*8 + (t >> 5);
        int d0 = (t & 31) * 8;
        float s8[8];
        #pragma unroll
        for(int e=0;e<8;e++) s8[e]=0.f;
        #pragma unroll
        for(int jc=0; jc<JC; jc++){
            u16x8 v = *reinterpret_cast<const u16x8*>(&attp[((size_t)(jc*BB + b)*NN + j0 + rr)*DD + d0]);
            #pragma unroll
            for(int e=0;e<8;e++) s8[e] += bf2f(v[e]);
        }
        u16x8 pack;
        #pragma unroll
        for(int e=0;e<8;e++) pack[e] = f2bf(s8[e]);
        *reinterpret_cast<u16x8*>(&ab[rr][d0]) = pack;
    }
    __syncthreads();

    // MFMA GEMM: wave wv handles n-tiles 4wv..4wv+3, M=16 all-real
    {
        int wv = t>>6, l = t&63, lr = l&15, kg = l>>4;
        f32x4 acc0 = (f32x4){0.f,0.f,0.f,0.f};
        f32x4 acc1 = (f32x4){0.f,0.f,0.f,0.f};
        f32x4 acc2 = (f32x4){0.f,0.f,0.f,0.f};
        f32x4 acc3 = (f32x4){0.f,0.f,0.f,0.f};
        #pragma unroll
        for(int ks=0; ks<8; ks++){
            bf16x8 a = *reinterpret_cast<const bf16x8*>(&ab[lr][ks*32 + kg*8]);
            bf16x8 b0 = *reinterpret_cast<const bf16x8*>(WoT + (size_t)((wv*4+0)*16 + lr)*DD + ks*32 + kg*8);
            bf16x8 b1 = *reinterpret_cast<const bf16x8*>(WoT + (size_t)((wv*4+1)*16 + lr)*DD + ks*32 + kg*8);
            bf16x8 b2 = *reinterpret_cast<const bf16x8*>(WoT + (size_t)((wv*4+2)*16 + lr)*DD + ks*32 + kg*8);
            bf16x8 b3 = *reinterpret_cast<const bf16x8*>(WoT + (size_t)((wv*4+3)*16 + lr)*DD + ks*32 + kg*8);
            acc0 = __builtin_amdgcn_mfma_f32_16x16x32_bf16(a, b0, acc0, 0,0,0);
            acc1 = __builtin_amdgcn_mfma_f32_16x16x32_bf16(a, b1, acc1, 0,0,0);
            acc2 = __builtin_amdgcn_mfma_f32_16x16x32_bf16(a, b2, acc2, 0,0,0);
            acc3 = __builtin_amdgcn_mfma_f32_16x16x32_bf16(a, b3, acc3, 0,0,0);
        }
        #pragma unroll
        for(int rg=0; rg<4; rg++){
            int i = kg*4 + rg;
            fbo[i][(wv*4+0)*16 + lr] = acc0[rg];
            fbo[i][(wv*4+1)*16 + lr] = acc1[rg];
            fbo[i][(wv*4+2)*16 + lr] = acc2[rg];
            fbo[i][(wv*4+3)*16 + lr] = acc3[rg];
        }
    }
    __syncthreads();

    // residual + LN (thread t = col)
    float accr[16];
    float bb = bo[t];
    #pragma unroll
    for(int r=0;r<16;r++) accr[r] = fbo[r][t] + bb + x[((size_t)r0+r)*DD + t];
    __syncthreads();
    #pragma unroll
    for(int r=0;r<16;r++) fbo[r][t] = accr[r];
    __syncthreads();
    {
        int rr = t>>4, seg = t&15;
        float s=0.f, sqs=0.f;
        #pragma unroll
        for(int e=0;e<16;e++){
            float y = fbo[rr][seg*16+e];
            s += y; sqs += y*y;
        }
        ps[rr][seg][0]=s; ps[rr][seg][1]=sqs;
    }
    __syncthreads();
    if(t<16){
        float s=0.f, sqs=0.f;
        #pragma unroll
        for(int e=0;e<16;e++){ s+=ps[t][e][0]; sqs+=ps[t][e][1]; }
        float mu = s/256.f;
        float var = sqs/256.f - mu*mu;
        muL[t]=mu; rsL[t]=rsqrtf(var+EPS);
    }
    __syncthreads();
    float gg = g[t], bl = bln[t];
    #pragma unroll
    for(int r=0;r<16;r++){
        out[((size_t)r0+r)*DD + t] = (accr[r]-muL[r])*rsL[r]*gg + bl;
    }
}

extern "C" void kernel_launch(void* const* d_in, const int* in_sizes, int n_in,
                              void* d_out, int out_size, void* d_ws, size_t ws_size,
                              hipStream_t stream) {
    const float* x    = (const float*)d_in[0];
    const int*   adj  = (const int*)d_in[1];
    const float* Wq   = (const float*)d_in[2];
    const float* bq   = (const float*)d_in[3];
    const float* Wk   = (const float*)d_in[4];
    const float* bk   = (const float*)d_in[5];
    const float* Wv   = (const float*)d_in[6];
    const float* bv   = (const float*)d_in[7];
    const float* aa   = (const float*)d_in[8];
    const float* Wo   = (const float*)d_in[9];
    const float* bo   = (const float*)d_in[10];
    const float* lng  = (const float*)d_in[11];
    const float* lnb  = (const float*)d_in[12];

    float* out0  = (float*)d_out;                  // (B,N,D)
    float* meanw = out0 + (size_t)BB*NN*DD;        // (B,N,N)

    char* wsb = (char*)d_ws;
    float* cq   = (float*)wsb;                                    // 16
    float* ck   = cq + 16;                                        // 16
    float* Mk   = ck + 16;                                        // 16 (+pad)
    float* sqv  = Mk + 80;                                        // 32768
    float* skH  = sqv + 32768;                                    // 32768
    float* Madj = skH + 32768;                                    // 32768
    unsigned* adjm = (unsigned*)(Madj + 32768);                   // BB*NN*64 u32 = 1MB
    ushort* uqkb= (ushort*)(adjm + (size_t)BB*NN*64);             // 16*256 u16
    ushort* WoT = uqkb + 16*DD;                                   // 256*256 u16
    ushort* WvT = WoT + (size_t)DD*DD;                            // 256*256 u16
    ushort* vT  = WvT + (size_t)DD*DD;                            // BB*DD*NN u16
    ushort* attp= vT + (size_t)BB*DD*NN;                          // JC*BB*NN*DD u16

    k_prep<<<136, 256, 0, stream>>>(Wq, bq, Wk, bk, aa, Wo, Wv, uqkb, cq, ck, WoT, WvT);
    k_sqskv<<<(BB*NN)/16, 256, 0, stream>>>(x, bv, uqkb, WvT, cq, ck, vT, sqv, skH);
    k_maxsk<<<BB*HH, 256, 0, stream>>>(skH, Mk);
    k_denom<<<(BB*NN)/2, 256, 0, stream>>>(adj, sqv, skH, Mk, Madj, adjm);
    k_attn<<<dim3(NN/TI, BB, JC), 256, 0, stream>>>(adjm, sqv, skH, Madj, vT, meanw, attp);
    k_out<<<(BB*NN)/16, 256, 0, stream>>>(attp, x, WoT, bo, lng, lnb, out0);
}